// Round 8
// baseline (325.351 us; speedup 1.0000x reference)
//
#include <hip/hip_runtime.h>

#define NPAR 384
#define NEPI 384
#define DD   256
#define NTAB 4096
#define SMAX 96.0f
#define SDELTA (SMAX / NTAB)
#define SINVD (NTAB / SMAX)

using bf16x8 = __bf16 __attribute__((ext_vector_type(8)));
using bf16x2 = __bf16 __attribute__((ext_vector_type(2)));
using f32x4  = float __attribute__((ext_vector_type(4)));

#if defined(__has_builtin)
#if __has_builtin(__builtin_amdgcn_cvt_pk_bf16_f32)
#define HAVE_PK_BF16 1
#endif
#if __has_builtin(__builtin_amdgcn_rcpf)
#define HAVE_RCPF 1
#endif
#endif

__device__ __forceinline__ float fastrcp(float x) {
#ifdef HAVE_RCPF
  return __builtin_amdgcn_rcpf(x);   // v_rcp_f32, ~1 ulp — plenty for bf16 outputs
#else
  return 1.0f / x;
#endif
}
__device__ __forceinline__ float sigm(float x) { return fastrcp(1.0f + __expf(-x)); }
__device__ __forceinline__ float silu(float x) { return x * fastrcp(1.0f + __expf(-x)); }
__device__ __forceinline__ unsigned short f2bf(float f) {
  unsigned u = __float_as_uint(f);
  u += 0x7fffu + ((u >> 16) & 1u);
  return (unsigned short)(u >> 16);
}
__device__ __forceinline__ float bf2f(unsigned u16) {
  return __uint_as_float(u16 << 16);
}
__device__ __forceinline__ uint2 pack4(float a, float b, float c, float d) {
  uint2 r;
#ifdef HAVE_PK_BF16
  bf16x2 lo = __builtin_amdgcn_cvt_pk_bf16_f32(a, b);
  bf16x2 hi = __builtin_amdgcn_cvt_pk_bf16_f32(c, d);
  r.x = __builtin_bit_cast(unsigned, lo);
  r.y = __builtin_bit_cast(unsigned, hi);
#else
  r.x = (unsigned)f2bf(a) | ((unsigned)f2bf(b) << 16);
  r.y = (unsigned)f2bf(c) | ((unsigned)f2bf(d) << 16);
#endif
  return r;
}

// write one element into MFMA-packed layout: wpack[slot][k][n]
__device__ __forceinline__ void store_packed(unsigned short* __restrict__ wp,
                                             int slot, int k, int n, float v) {
  const int ks = k >> 5, lhi = (k >> 3) & 3, j = k & 7;
  const int tile = n >> 4, llo = n & 15;
  const int lane = lhi * 16 + llo;
  wp[slot * 65536 + (((ks * 16 + tile) * 64 + lane) << 3) + j] = f2bf(v);
}

// ---------------- fused precompute kernel ----------------
// [0,256) fold Mr/Ma (2 rows/block, writes wpack slots 0/1 packed) ; [256] cvec ;
// [257,321) gvec ; [321,577) Wqk = wq@wk^T (writes slot 4 packed) ;
// [577,961) mm_rows4 (4 rows/block) ; [961,1473) pack int_w2 (slot 2) / wg (slot 3)

__global__ void prep_kernel(
    const float* __restrict__ H, const float* __restrict__ wl,
    const float* __restrict__ wr, const float* __restrict__ int_w1,
    const float* __restrict__ res_w2, const float* __restrict__ atom_w2,
    const float* __restrict__ res_b2, const float* __restrict__ atom_b2,
    const float* __restrict__ int_b1, const float* __restrict__ simw,
    const float* __restrict__ wq_b, const float* __restrict__ wk_w,
    const float* __restrict__ wq_w, const float* __restrict__ int_w2,
    const float* __restrict__ wg_w,
    float* __restrict__ Hpl, float* __restrict__ Her,
    float* __restrict__ P1, float* __restrict__ P2,
    float* __restrict__ cvec, float* __restrict__ gv,
    unsigned short* __restrict__ wpack) {
  __shared__ float sbuf[1024];
  const int b = blockIdx.x, t = threadIdx.x;
  if (b < 256) {
    const bool isMa = b >= 128;
    const int i0 = (b & 127) * 2;
    const float wmix = 1.0f / (1.0f + __expf(-simw[0]));
    const float sc = isMa ? (1.0f - wmix) : wmix;
    const float* W2 = isMa ? atom_w2 : res_w2;
    sbuf[t] = W2[i0 * 256 + t];
    sbuf[256 + t] = W2[(i0 + 1) * 256 + t];
    __syncthreads();
    float a0 = 0.f, a1 = 0.f;
#pragma unroll 8
    for (int k = 0; k < 256; ++k) {
      const float w = int_w1[(512 + k) * 256 + t];
      a0 = fmaf(sbuf[k], w, a0);
      a1 = fmaf(sbuf[256 + k], w, a1);
    }
    const int slot = isMa ? 1 : 0;
    store_packed(wpack, slot, i0, t, a0 * sc);
    store_packed(wpack, slot, i0 + 1, t, a1 * sc);
  } else if (b == 256) {
    const float wmix = 1.0f / (1.0f + __expf(-simw[0]));
    float acc = int_b1[t];
#pragma unroll 8
    for (int k = 0; k < 256; ++k) {
      float bm = wmix * res_b2[k] + (1.0f - wmix) * atom_b2[k];
      acc += bm * int_w1[(512 + k) * 256 + t];
    }
    cvec[t] = acc;
  } else if (b < 321) {
    const int lane = t & 63, w = t >> 6;
    const int d = (b - 257) * 4 + w;
    float acc = 0.f;
#pragma unroll
    for (int i = 0; i < 4; ++i) {
      const int c = i * 64 + lane;
      acc += wk_w[d * 256 + c] * wq_b[c];
    }
    acc += __shfl_xor(acc, 1);
    acc += __shfl_xor(acc, 2);
    acc += __shfl_xor(acc, 4);
    acc += __shfl_xor(acc, 8);
    acc += __shfl_xor(acc, 16);
    acc += __shfl_xor(acc, 32);
    if (lane == 0) gv[d] = acc;
  } else if (b < 577) {
    const int r = b - 321;
    sbuf[t] = wq_w[r * 256 + t];
    __syncthreads();
    const float* wkrow = wk_w + t * 256;
    float a0 = 0.f, a1 = 0.f, a2 = 0.f, a3 = 0.f;
#pragma unroll 4
    for (int k = 0; k < 256; k += 4) {
      const f32x4 wv4 = *reinterpret_cast<const f32x4*>(&wkrow[k]);
      a0 = fmaf(sbuf[k + 0], wv4[0], a0);
      a1 = fmaf(sbuf[k + 1], wv4[1], a1);
      a2 = fmaf(sbuf[k + 2], wv4[2], a2);
      a3 = fmaf(sbuf[k + 3], wv4[3], a3);
    }
    store_packed(wpack, 4, r, t, (a0 + a1) + (a2 + a3));
  } else if (b < 961) {
    const int idx = b - 577;
    const int seg = idx / 96, r0 = (idx % 96) * 4;
    const float* A;
    const float* B;
    float* C;
    switch (seg) {
      case 0:  A = H + r0 * 256;            B = wl;              C = Hpl + r0 * 256; break;
      case 1:  A = H + (NPAR + r0) * 256;   B = wr;              C = Her + r0 * 256; break;
      case 2:  A = H + r0 * 256;            B = int_w1;          C = P1 + r0 * 256;  break;
      default: A = H + (NPAR + r0) * 256;   B = int_w1 + 65536;  C = P2 + r0 * 256;  break;
    }
#pragma unroll
    for (int j = 0; j < 4; ++j) sbuf[j * 256 + t] = A[j * 256 + t];
    __syncthreads();
    float a0 = 0.f, a1 = 0.f, a2 = 0.f, a3 = 0.f;
#pragma unroll 8
    for (int k = 0; k < 256; ++k) {
      const float bv = B[k * 256 + t];
      a0 = fmaf(sbuf[k], bv, a0);
      a1 = fmaf(sbuf[256 + k], bv, a1);
      a2 = fmaf(sbuf[512 + k], bv, a2);
      a3 = fmaf(sbuf[768 + k], bv, a3);
    }
    C[t] = a0;
    C[256 + t] = a1;
    C[512 + t] = a2;
    C[768 + t] = a3;
  } else {
    // pack int_w2 -> slot 2, wg -> slot 3 (same indexing as old pack_kernel)
    const int idx = (b - 961) * 256 + t;       // 0 .. 2*65536-1
    const int m = idx >> 16;                   // 0 or 1
    const int r = idx & 65535;
    const int chunk = r >> 9;
    const int lane = (r >> 3) & 63;
    const int j = r & 7;
    const int k = (chunk >> 4) * 32 + (lane >> 4) * 8 + j;
    const int n = (chunk & 15) * 16 + (lane & 15);
    const float* src = (m == 0) ? int_w2 : wg_w;
    wpack[(2 + m) * 65536 + r] = f2bf(src[k * 256 + n]);
  }
}

// ---------------- shared GEMM helpers ----------------

template <int MT>
__device__ __forceinline__ void zero_accN(f32x4 (&acc)[MT][4]) {
#pragma unroll
  for (int mt = 0; mt < MT; ++mt)
#pragma unroll
    for (int nt = 0; nt < 4; ++nt)
      acc[mt][nt] = (f32x4){0.f, 0.f, 0.f, 0.f};
}

// transposed-acc: mfma(Wfrag, ActFrag) -> acc^T[d][e]; tile0 = first output-d tile
template <int MT>
__device__ __forceinline__ void gemmN(f32x4 (&acc)[MT][4],
                                      const unsigned short* __restrict__ wp,
                                      const unsigned short* ub, int lane, int tile0) {
  const int l15 = lane & 15, l4 = lane >> 4;
#pragma unroll
  for (int ks = 0; ks < 8; ++ks) {
    bf16x8 a[MT];
#pragma unroll
    for (int mt = 0; mt < MT; ++mt)
      a[mt] = *reinterpret_cast<const bf16x8*>(wp + ((ks * 16 + tile0 + mt) * 64 + lane) * 8);
    __builtin_amdgcn_s_setprio(1);
#pragma unroll
    for (int nt = 0; nt < 4; ++nt) {
      bf16x8 b = *reinterpret_cast<const bf16x8*>(ub + (nt * 16 + l15) * 264 + ks * 32 + l4 * 8);
#pragma unroll
      for (int mt = 0; mt < MT; ++mt)
        acc[mt][nt] = __builtin_amdgcn_mfma_f32_16x16x32_bf16(a[mt], b, acc[mt][nt], 0, 0, 0);
    }
    __builtin_amdgcn_s_setprio(0);
  }
}

// fill ubuf[e][d] = silu(Sv[e]*w1[d] + b1[d])
__device__ __forceinline__ void fill_u(unsigned short* ub, const float* Sv,
                                       const float* __restrict__ w1,
                                       const float* __restrict__ b1, int t) {
  const int dg = t & 31, rb = t >> 5;
  const f32x4 w1a = *reinterpret_cast<const f32x4*>(&w1[dg * 8]);
  const f32x4 w1b = *reinterpret_cast<const f32x4*>(&w1[dg * 8 + 4]);
  const f32x4 b1a = *reinterpret_cast<const f32x4*>(&b1[dg * 8]);
  const f32x4 b1b = *reinterpret_cast<const f32x4*>(&b1[dg * 8 + 4]);
#pragma unroll
  for (int i = 0; i < 8; ++i) {
    const int e = rb + i * 8;
    const float s = Sv[e];
    uint2 lo = pack4(silu(fmaf(s, w1a[0], b1a[0])), silu(fmaf(s, w1a[1], b1a[1])),
                     silu(fmaf(s, w1a[2], b1a[2])), silu(fmaf(s, w1a[3], b1a[3])));
    uint2 hi = pack4(silu(fmaf(s, w1b[0], b1b[0])), silu(fmaf(s, w1b[1], b1b[1])),
                     silu(fmaf(s, w1b[2], b1b[2])), silu(fmaf(s, w1b[3], b1b[3])));
    uint4 pk = {lo.x, lo.y, hi.x, hi.y};
    *reinterpret_cast<uint4*>(&ub[e * 264 + dg * 8]) = pk;
  }
}

// ---------------- table build: tabF[n][d] = F(n*SDELTA)[d], fp32 out ----------------

__global__ __launch_bounds__(256, 3) void tab_kernel(
    const float* __restrict__ res_w1, const float* __restrict__ res_b1,
    const float* __restrict__ atom_w1, const float* __restrict__ atom_b1,
    const unsigned short* __restrict__ wpack, float* __restrict__ tabF) {
  __shared__ __align__(16) unsigned short ubuf[64 * 264];
  __shared__ float Sv[64];
  const int t = threadIdx.x, lane = t & 63, wv = t >> 6;
  const int l15 = lane & 15, l4 = lane >> 4;
  const int n0 = blockIdx.x * 64;
  if (t < 64) Sv[t] = (n0 + t) * SDELTA;
  __syncthreads();
  f32x4 acc[4][4];
  zero_accN<4>(acc);
  fill_u(ubuf, Sv, res_w1, res_b1, t);
  __syncthreads();
  gemmN<4>(acc, wpack + 0 * 65536, ubuf, lane, wv * 4);
  __syncthreads();
  fill_u(ubuf, Sv, atom_w1, atom_b1, t);
  __syncthreads();
  gemmN<4>(acc, wpack + 1 * 65536, ubuf, lane, wv * 4);
#pragma unroll
  for (int mt = 0; mt < 4; ++mt) {
    const int d = wv * 64 + mt * 16 + l4 * 4;
#pragma unroll
    for (int nt = 0; nt < 4; ++nt) {
      const int n = n0 + nt * 16 + l15;
      *reinterpret_cast<f32x4*>(&tabF[n * 256 + d]) = acc[mt][nt];
    }
  }
}

// ---------------- pairwise kernel: 512 threads / 8 waves, acc[2][4] per wave -------
// TLP push done RIGHT this time: halve the per-wave accumulator (32 VGPR) so the
// whole kernel fits <=64 VGPR -> 8 waves/SIMD quantum -> 32 waves/CU (2x R7's 16).
// Work per block, LDS (35328B), grid (2304, XCD-swizzled) unchanged.
// (R6 lesson was: never CAP registers below the accumulator; here we SHRANK the
//  accumulator instead.)

__global__ __launch_bounds__(512, 8) void pair_kernel(
    const float* __restrict__ Xg, const float* __restrict__ tabF,
    const float* __restrict__ int_b2, const float* __restrict__ wg_b,
    const unsigned short* __restrict__ wpack, const float* __restrict__ cvec,
    const float* __restrict__ P1, const float* __restrict__ P2,
    const float* __restrict__ Hpl, const float* __restrict__ Her,
    float* __restrict__ ftri, unsigned short* __restrict__ Zsw) {
  __shared__ __align__(16) unsigned short ubuf[64 * 264];
  __shared__ float Sv[64];
  __shared__ float pc[DD];
  const int t = threadIdx.x, lane = t & 63, wv = t >> 6;   // wv 0..7
  const int l15 = lane & 15, l4 = lane >> 4;
  const int wg = (blockIdx.x & 7) * 288 + (blockIdx.x >> 3);  // bijective XCD swizzle
  const int p = wg / 6, cc = wg % 6, e0 = cc * 64;
  const int d0 = wv * 32;                                   // 32 d-columns per wave

  if (t < 64) {
    const int e = e0 + t;
    float dx = Xg[p * 42 + 3] - Xg[(NPAR + e) * 42 + 3];
    float dy = Xg[p * 42 + 4] - Xg[(NPAR + e) * 42 + 4];
    float dz = Xg[p * 42 + 5] - Xg[(NPAR + e) * 42 + 5];
    Sv[t] = dx * dx + dy * dy + dz * dz;
  }
  if (t < DD) pc[t] = P1[p * DD + t] + cvec[t];
  __syncthreads();

  // h-fill: h[e][d] = silu(lerp(tabF, S[e])[d] + pc[d] + P2[e][d]) -> ubuf
  // 512 threads: dg = t&31 (d-chunk), rb = t>>5 in [0,16), e = rb + i*16
  {
    const int dg = t & 31, rb = t >> 5;
    const f32x4 pca = *reinterpret_cast<const f32x4*>(&pc[dg * 8]);
    const f32x4 pcb = *reinterpret_cast<const f32x4*>(&pc[dg * 8 + 4]);
#pragma unroll
    for (int i = 0; i < 4; ++i) {
      const int e = rb + i * 16;
      float sv = Sv[e] * SINVD;
      int idx = (int)sv;
      idx = idx > (NTAB - 2) ? (NTAB - 2) : idx;
      const float fr = sv - (float)idx;
      const f32x4 t0a = *reinterpret_cast<const f32x4*>(&tabF[idx * 256 + dg * 8]);
      const f32x4 t0b = *reinterpret_cast<const f32x4*>(&tabF[idx * 256 + dg * 8 + 4]);
      const f32x4 t1a = *reinterpret_cast<const f32x4*>(&tabF[(idx + 1) * 256 + dg * 8]);
      const f32x4 t1b = *reinterpret_cast<const f32x4*>(&tabF[(idx + 1) * 256 + dg * 8 + 4]);
      const f32x4 p2a = *reinterpret_cast<const f32x4*>(&P2[(e0 + e) * DD + dg * 8]);
      const f32x4 p2b = *reinterpret_cast<const f32x4*>(&P2[(e0 + e) * DD + dg * 8 + 4]);
      float z0 = fmaf(fr, t1a[0] - t0a[0], t0a[0]) + pca[0] + p2a[0];
      float z1 = fmaf(fr, t1a[1] - t0a[1], t0a[1]) + pca[1] + p2a[1];
      float z2 = fmaf(fr, t1a[2] - t0a[2], t0a[2]) + pca[2] + p2a[2];
      float z3 = fmaf(fr, t1a[3] - t0a[3], t0a[3]) + pca[3] + p2a[3];
      float z4 = fmaf(fr, t1b[0] - t0b[0], t0b[0]) + pcb[0] + p2b[0];
      float z5 = fmaf(fr, t1b[1] - t0b[1], t0b[1]) + pcb[1] + p2b[1];
      float z6 = fmaf(fr, t1b[2] - t0b[2], t0b[2]) + pcb[2] + p2b[2];
      float z7 = fmaf(fr, t1b[3] - t0b[3], t0b[3]) + pcb[3] + p2b[3];
      uint2 lo = pack4(silu(z0), silu(z1), silu(z2), silu(z3));
      uint2 hi = pack4(silu(z4), silu(z5), silu(z6), silu(z7));
      uint4 pk = {lo.x, lo.y, hi.x, hi.y};
      *reinterpret_cast<uint4*>(&ubuf[e * 264 + dg * 8]) = pk;
    }
  }
  __syncthreads();

  // Z = h @ int_w2 + int_b2 -> ubuf  (each wave: output-d tiles wv*2, wv*2+1)
  f32x4 acc[2][4];
  zero_accN<2>(acc);
  gemmN<2>(acc, wpack + 2 * 65536, ubuf, lane, wv * 2);
  __syncthreads();
#pragma unroll
  for (int mt = 0; mt < 2; ++mt) {
    const int d = d0 + mt * 16 + l4 * 4;
    const f32x4 bb = *reinterpret_cast<const f32x4*>(&int_b2[d]);
#pragma unroll
    for (int nt = 0; nt < 4; ++nt) {
      const int e = nt * 16 + l15;
      *reinterpret_cast<uint2*>(&ubuf[e * 264 + d]) =
          pack4(acc[mt][nt][0] + bb[0], acc[mt][nt][1] + bb[1],
                acc[mt][nt][2] + bb[2], acc[mt][nt][3] + bb[3]);
    }
  }
  __syncthreads();

  // swizzled MFMA-fragment-order store: wave pair (2k,2k+1) shares grp cc*4+k,
  // splitting the 8 ks halves (even wave: ks 0-3, odd wave: ks 4-7)
  {
    const int g = wv >> 1, ksb = (wv & 1) * 4;
    unsigned short* Zd = Zsw + (size_t)p * 98304 + (size_t)(cc * 4 + g) * 4096 + lane * 8;
    const int row = g * 16 + l15;
#pragma unroll
    for (int k2 = 0; k2 < 4; ++k2) {
      const int ks = ksb + k2;
      *reinterpret_cast<uint4*>(Zd + ks * 512) =
          *reinterpret_cast<const uint4*>(&ubuf[row * 264 + ks * 32 + l4 * 8]);
    }
  }

  // gate: f_tri[d] += Hpl[p][d] * sum_e sigm(Z@wg + b) * Her[e][d]
  zero_accN<2>(acc);
  gemmN<2>(acc, wpack + 3 * 65536, ubuf, lane, wv * 2);
#pragma unroll
  for (int mt = 0; mt < 2; ++mt) {
    const int d = d0 + mt * 16 + l4 * 4;
    const f32x4 bb = *reinterpret_cast<const f32x4*>(&wg_b[d]);
    const f32x4 hl = *reinterpret_cast<const f32x4*>(&Hpl[p * DD + d]);
    f32x4 fs = (f32x4){0.f, 0.f, 0.f, 0.f};
#pragma unroll
    for (int nt = 0; nt < 4; ++nt) {
      const int e = e0 + nt * 16 + l15;
      const f32x4 hr = *reinterpret_cast<const f32x4*>(&Her[e * DD + d]);
#pragma unroll
      for (int r = 0; r < 4; ++r)
        fs[r] += sigm(acc[mt][nt][r] + bb[r]) * hr[r];
    }
#pragma unroll
    for (int r = 0; r < 4; ++r) {
      float v = fs[r] * hl[r];
      v += __shfl_xor(v, 1);
      v += __shfl_xor(v, 2);
      v += __shfl_xor(v, 4);
      v += __shfl_xor(v, 8);
      if (l15 == 0) atomicAdd(&ftri[p * DD + d + r], v);
    }
  }
}

// ---------------- fused attention kernel: block = (p, 32-row chunk) ----------------

__global__ __launch_bounds__(256, 4) void attn_kernel(
    const unsigned short* __restrict__ Zsw, const float* __restrict__ gv,
    const unsigned short* __restrict__ wpack, float* __restrict__ cbufg) {
  __shared__ __align__(16) unsigned short Tc[32 * 264];
  __shared__ float red[128];
  __shared__ float red2[128];
  const int t = threadIdx.x, lane = t & 63, wv = t >> 6;
  const int l15 = lane & 15, l4 = lane >> 4;
  const int xcd = blockIdx.x & 7, inner = blockIdx.x >> 3;
  const int p = (inner / 12) * 8 + xcd, c = inner % 12;
  const unsigned short* Zsp = Zsw + (size_t)p * 98304;
  const unsigned short* wqk = wpack + 4 * 65536;

  // T' = (Zc @ Wqk + gv) / 16 for 32 rows (groups 2c, 2c+1), double-buffered
  {
    f32x4 ta[4][2];
#pragma unroll
    for (int mt = 0; mt < 4; ++mt)
#pragma unroll
      for (int nt = 0; nt < 2; ++nt) ta[mt][nt] = (f32x4){0.f, 0.f, 0.f, 0.f};
    const unsigned short* Tb = Zsp + (size_t)(c * 2) * 4096 + lane * 8;
    bf16x8 bcur[2], bnxt[2];
#pragma unroll
    for (int nt = 0; nt < 2; ++nt)
      bcur[nt] = *reinterpret_cast<const bf16x8*>(Tb + nt * 4096);
#pragma unroll
    for (int ks = 0; ks < 8; ++ks) {
      if (ks < 7) {
#pragma unroll
        for (int nt = 0; nt < 2; ++nt)
          bnxt[nt] = *reinterpret_cast<const bf16x8*>(Tb + nt * 4096 + (ks + 1) * 512);
      }
      bf16x8 a[4];
#pragma unroll
      for (int mt = 0; mt < 4; ++mt)
        a[mt] = *reinterpret_cast<const bf16x8*>(wqk + ((ks * 16 + wv * 4 + mt) * 64 + lane) * 8);
      __builtin_amdgcn_s_setprio(1);
#pragma unroll
      for (int nt = 0; nt < 2; ++nt)
#pragma unroll
        for (int mt = 0; mt < 4; ++mt)
          ta[mt][nt] = __builtin_amdgcn_mfma_f32_16x16x32_bf16(a[mt], bcur[nt], ta[mt][nt], 0, 0, 0);
      __builtin_amdgcn_s_setprio(0);
      if (ks < 7) {
#pragma unroll
        for (int nt = 0; nt < 2; ++nt) bcur[nt] = bnxt[nt];
      }
    }
#pragma unroll
    for (int mt = 0; mt < 4; ++mt) {
      const int d = wv * 64 + mt * 16 + l4 * 4;
      const f32x4 gq = *reinterpret_cast<const f32x4*>(&gv[d]);
#pragma unroll
      for (int nt = 0; nt < 2; ++nt) {
        const int e = nt * 16 + l15;
        *reinterpret_cast<uint2*>(&Tc[e * 264 + d]) =
            pack4((ta[mt][nt][0] + gq[0]) * 0.0625f, (ta[mt][nt][1] + gq[1]) * 0.0625f,
                  (ta[mt][nt][2] + gq[2]) * 0.0625f, (ta[mt][nt][3] + gq[3]) * 0.0625f);
      }
    }
  }
  __syncthreads();

  // S = Tc @ Z^T; a-frags from LDS, b-frags 3+3 rolling prefetch
  f32x4 sc[2][6];
#pragma unroll
  for (int mt = 0; mt < 2; ++mt)
#pragma unroll
    for (int s = 0; s < 6; ++s) sc[mt][s] = (f32x4){0.f, 0.f, 0.f, 0.f};

  {
    const unsigned short* Sb = Zsp + (size_t)wv * 4096 + lane * 8;
    bf16x8 b0[3], b1[3];
#pragma unroll
    for (int j = 0; j < 3; ++j)
      b0[j] = *reinterpret_cast<const bf16x8*>(Sb + j * 16384);
#pragma unroll
    for (int ks = 0; ks < 8; ++ks) {
#pragma unroll
      for (int j = 0; j < 3; ++j)
        b1[j] = *reinterpret_cast<const bf16x8*>(Sb + (3 + j) * 16384 + ks * 512);
      bf16x8 a[2];
#pragma unroll
      for (int mt = 0; mt < 2; ++mt)
        a[mt] = *reinterpret_cast<const bf16x8*>(&Tc[(mt * 16 + l15) * 264 + ks * 32 + l4 * 8]);
      __builtin_amdgcn_s_setprio(1);
#pragma unroll
      for (int j = 0; j < 3; ++j)
#pragma unroll
        for (int mt = 0; mt < 2; ++mt)
          sc[mt][j] = __builtin_amdgcn_mfma_f32_16x16x32_bf16(a[mt], b0[j], sc[mt][j], 0, 0, 0);
      __builtin_amdgcn_s_setprio(0);
      if (ks < 7) {
#pragma unroll
        for (int j = 0; j < 3; ++j)
          b0[j] = *reinterpret_cast<const bf16x8*>(Sb + j * 16384 + (ks + 1) * 512);
      }
      __builtin_amdgcn_s_setprio(1);
#pragma unroll
      for (int j = 0; j < 3; ++j)
#pragma unroll
        for (int mt = 0; mt < 2; ++mt)
          sc[mt][3 + j] = __builtin_amdgcn_mfma_f32_16x16x32_bf16(a[mt], b1[j], sc[mt][3 + j], 0, 0, 0);
      __builtin_amdgcn_s_setprio(0);
    }
  }

  // softmax over f (384 cols), rows e = mt*16 + l4*4 + r (32 rows)
  float rmax[2][4];
#pragma unroll
  for (int mt = 0; mt < 2; ++mt) {
#pragma unroll
    for (int r = 0; r < 4; ++r) {
      float m = -1e30f;
#pragma unroll
      for (int s = 0; s < 6; ++s) m = fmaxf(m, sc[mt][s][r]);
      m = fmaxf(m, __shfl_xor(m, 1));
      m = fmaxf(m, __shfl_xor(m, 2));
      m = fmaxf(m, __shfl_xor(m, 4));
      m = fmaxf(m, __shfl_xor(m, 8));
      rmax[mt][r] = m;
    }
  }
  if (l15 == 0) {
#pragma unroll
    for (int mt = 0; mt < 2; ++mt)
#pragma unroll
      for (int r = 0; r < 4; ++r)
        red[wv * 32 + mt * 16 + l4 * 4 + r] = rmax[mt][r];
  }
  __syncthreads();
#pragma unroll
  for (int mt = 0; mt < 2; ++mt) {
#pragma unroll
    for (int r = 0; r < 4; ++r) {
      const int row = mt * 16 + l4 * 4 + r;
      rmax[mt][r] = fmaxf(fmaxf(red[row], red[32 + row]), fmaxf(red[64 + row], red[96 + row]));
    }
  }

  float rsum[2][4];
#pragma unroll
  for (int mt = 0; mt < 2; ++mt) {
#pragma unroll
    for (int r = 0; r < 4; ++r) {
      float sSum = 0.f;
#pragma unroll
      for (int s = 0; s < 6; ++s) {
        float e = __expf(sc[mt][s][r] - rmax[mt][r]);
        sc[mt][s][r] = e;
        sSum += e;
      }
      sSum += __shfl_xor(sSum, 1);
      sSum += __shfl_xor(sSum, 2);
      sSum += __shfl_xor(sSum, 4);
      sSum += __shfl_xor(sSum, 8);
      rsum[mt][r] = sSum;
    }
  }
  if (l15 == 0) {
#pragma unroll
    for (int mt = 0; mt < 2; ++mt)
#pragma unroll
      for (int r = 0; r < 4; ++r)
        red2[wv * 32 + mt * 16 + l4 * 4 + r] = rsum[mt][r];
  }
  __syncthreads();
  float rinv[2][4];
#pragma unroll
  for (int mt = 0; mt < 2; ++mt) {
#pragma unroll
    for (int r = 0; r < 4; ++r) {
      const int row = mt * 16 + l4 * 4 + r;
      rinv[mt][r] = fastrcp(red2[row] + red2[32 + row] + red2[64 + row] + red2[96 + row]);
    }
  }

  // column sums of A over this chunk's 32 rows -> cbufg
#pragma unroll
  for (int s = 0; s < 6; ++s) {
    float v = 0.f;
#pragma unroll
    for (int mt = 0; mt < 2; ++mt)
#pragma unroll
      for (int r = 0; r < 4; ++r)
        v += sc[mt][s][r] * rinv[mt][r];
    v += __shfl_xor(v, 16);
    v += __shfl_xor(v, 32);
    if (lane < 16)
      atomicAdd(&cbufg[p * NEPI + (s * 4 + wv) * 16 + lane], v);
  }
}

// ---------------- output part A: u[p][d] partial over one f-third ----------------

__global__ __launch_bounds__(256) void outa_kernel(
    const unsigned short* __restrict__ Zsw, const float* __restrict__ cbufg,
    float* __restrict__ ubufg) {
  __shared__ float cb[128];
  __shared__ float part[16][257];
  const int p = blockIdx.x / 3, th = blockIdx.x % 3, g0 = th * 8;
  const int t = threadIdx.x;
  const int lane = t & 63, wv = t >> 6;
  const int l15 = lane & 15, l4 = lane >> 4;
  if (t < 128) cb[t] = cbufg[p * NEPI + g0 * 16 + t];
  __syncthreads();
  const unsigned short* Zsp = Zsw + (size_t)p * 98304;
  float a16[16];
#pragma unroll
  for (int j = 0; j < 16; ++j) a16[j] = 0.f;
#pragma unroll
  for (int gr = 0; gr < 8; ++gr) {
    const int grp = g0 + gr;
    const float w = cb[gr * 16 + l15];
    const uint4 z0 = *reinterpret_cast<const uint4*>(Zsp + grp * 4096 + wv * 512 + lane * 8);
    const uint4 z1 = *reinterpret_cast<const uint4*>(Zsp + grp * 4096 + (wv + 4) * 512 + lane * 8);
    a16[0] = fmaf(w, bf2f(z0.x & 0xffffu), a16[0]);
    a16[1] = fmaf(w, bf2f(z0.x >> 16), a16[1]);
    a16[2] = fmaf(w, bf2f(z0.y & 0xffffu), a16[2]);
    a16[3] = fmaf(w, bf2f(z0.y >> 16), a16[3]);
    a16[4] = fmaf(w, bf2f(z0.z & 0xffffu), a16[4]);
    a16[5] = fmaf(w, bf2f(z0.z >> 16), a16[5]);
    a16[6] = fmaf(w, bf2f(z0.w & 0xffffu), a16[6]);
    a16[7] = fmaf(w, bf2f(z0.w >> 16), a16[7]);
    a16[8]  = fmaf(w, bf2f(z1.x & 0xffffu), a16[8]);
    a16[9]  = fmaf(w, bf2f(z1.x >> 16), a16[9]);
    a16[10] = fmaf(w, bf2f(z1.y & 0xffffu), a16[10]);
    a16[11] = fmaf(w, bf2f(z1.y >> 16), a16[11]);
    a16[12] = fmaf(w, bf2f(z1.z & 0xffffu), a16[12]);
    a16[13] = fmaf(w, bf2f(z1.z >> 16), a16[13]);
    a16[14] = fmaf(w, bf2f(z1.w & 0xffffu), a16[14]);
    a16[15] = fmaf(w, bf2f(z1.w >> 16), a16[15]);
  }
#pragma unroll
  for (int j = 0; j < 8; ++j) part[l15][wv * 32 + l4 * 8 + j] = a16[j];
#pragma unroll
  for (int j = 0; j < 8; ++j) part[l15][128 + wv * 32 + l4 * 8 + j] = a16[8 + j];
  __syncthreads();
  float uu = 0.f;
#pragma unroll
  for (int g = 0; g < 16; ++g) uu += part[g][t];
  atomicAdd(&ubufg[p * DD + t], uu);
}

// ---------------- output part B: out[p] = (ftri + u@wv + 384*bv)/384 ----------------

__global__ __launch_bounds__(256) void out2_kernel(
    const float* __restrict__ ubufg, const float* __restrict__ ftri,
    const float* __restrict__ wvw, const float* __restrict__ wvb,
    float* __restrict__ out) {
  __shared__ float u[DD];
  const int p = blockIdx.x, t = threadIdx.x;
  u[t] = ubufg[p * DD + t];
  __syncthreads();
  float acc = ftri[p * DD + t] + 384.0f * wvb[t];
#pragma unroll 8
  for (int d = 0; d < DD; ++d)
    acc = fmaf(u[d], wvw[d * DD + t], acc);
  out[p * DD + t] = acc * (1.0f / 384.0f);
}

// ---------------- launch ----------------

extern "C" void kernel_launch(void* const* d_in, const int* in_sizes, int n_in,
                              void* d_out, int out_size, void* d_ws, size_t ws_size,
                              hipStream_t stream) {
  (void)in_sizes; (void)n_in; (void)out_size; (void)ws_size;
  const float* H = (const float*)d_in[0];
  const float* X = (const float*)d_in[1];
  const float* res_w1 = (const float*)d_in[4];
  const float* res_b1 = (const float*)d_in[5];
  const float* res_w2 = (const float*)d_in[6];
  const float* res_b2 = (const float*)d_in[7];
  const float* atom_w1 = (const float*)d_in[8];
  const float* atom_b1 = (const float*)d_in[9];
  const float* atom_w2 = (const float*)d_in[10];
  const float* atom_b2 = (const float*)d_in[11];
  const float* simw = (const float*)d_in[12];
  const float* int_w1 = (const float*)d_in[13];
  const float* int_b1 = (const float*)d_in[14];
  const float* int_w2 = (const float*)d_in[15];
  const float* int_b2 = (const float*)d_in[16];
  const float* wl = (const float*)d_in[17];
  const float* wr = (const float*)d_in[18];
  const float* wg_w = (const float*)d_in[19];
  const float* wg_b = (const float*)d_in[20];
  const float* wq_w = (const float*)d_in[21];
  const float* wq_b = (const float*)d_in[22];
  const float* wk_w = (const float*)d_in[23];
  const float* wv_w = (const float*)d_in[25];
  const float* wv_b = (const float*)d_in[26];

  char* ws = (char*)d_ws;
  unsigned short* wpack = (unsigned short*)(ws + 0);      //  655360 B (5 slots)
  float* cvec  = (float*)(ws + 655360);                   //    1024 B
  float* gv    = (float*)(ws + 656384);                   //    1024 B
  float* P1    = (float*)(ws + 657408);                   //  393216 B
  float* P2    = (float*)(ws + 1050624);                  //  393216 B
  float* Hpl   = (float*)(ws + 1443840);                  //  393216 B
  float* Her   = (float*)(ws + 1837056);                  //  393216 B
  float* ftri  = (float*)(ws + 2230272);                  //  393216 B
  float* cbufg = (float*)(ws + 2623488);                  //  589824 B
  float* ubufg = (float*)(ws + 3213312);                  //  393216 B
  unsigned short* Zsw = (unsigned short*)(ws + 3606528);  // 75497472 B
  float* tabF  = (float*)(ws + 79104000);                 //  4194304 B (NTAB x 256 fp32)

  // independent of all kernels: overlap the H-tail copy with the kernel chain
  hipMemcpyAsync((float*)d_out + NPAR * DD, H + NPAR * DD,
                 (1024 - NPAR) * DD * sizeof(float), hipMemcpyDeviceToDevice, stream);
  hipMemsetAsync(ftri, 0, 393216 + 589824 + 393216, stream);
  prep_kernel<<<1473, 256, 0, stream>>>(H, wl, wr, int_w1, res_w2, atom_w2,
                                        res_b2, atom_b2, int_b1, simw, wq_b, wk_w,
                                        wq_w, int_w2, wg_w,
                                        Hpl, Her, P1, P2, cvec, gv, wpack);
  tab_kernel<<<NTAB / 64, 256, 0, stream>>>(res_w1, res_b1, atom_w1, atom_b1, wpack, tabF);
  pair_kernel<<<2304, 512, 0, stream>>>(X, tabF, int_b2, wg_b, wpack, cvec,
                                        P1, P2, Hpl, Her, ftri, Zsw);
  attn_kernel<<<4608, 256, 0, stream>>>(Zsw, gv, wpack, cbufg);
  outa_kernel<<<1152, 256, 0, stream>>>(Zsw, cbufg, ubufg);
  out2_kernel<<<384, 256, 0, stream>>>(ubufg, ftri, wv_w, wv_b, (float*)d_out);
}

// Round 9
// 307.303 us; speedup vs baseline: 1.0587x; 1.0587x over previous
//
#include <hip/hip_runtime.h>

#define NPAR 384
#define NEPI 384
#define DD   256
#define NTAB 4096
#define SMAX 96.0f
#define SDELTA (SMAX / NTAB)
#define SINVD (NTAB / SMAX)

using bf16x8 = __bf16 __attribute__((ext_vector_type(8)));
using bf16x2 = __bf16 __attribute__((ext_vector_type(2)));
using f32x4  = float __attribute__((ext_vector_type(4)));

#if defined(__has_builtin)
#if __has_builtin(__builtin_amdgcn_cvt_pk_bf16_f32)
#define HAVE_PK_BF16 1
#endif
#if __has_builtin(__builtin_amdgcn_rcpf)
#define HAVE_RCPF 1
#endif
#endif

__device__ __forceinline__ float fastrcp(float x) {
#ifdef HAVE_RCPF
  return __builtin_amdgcn_rcpf(x);   // v_rcp_f32, ~1 ulp — plenty for bf16 outputs
#else
  return 1.0f / x;
#endif
}
__device__ __forceinline__ float sigm(float x) { return fastrcp(1.0f + __expf(-x)); }
__device__ __forceinline__ float silu(float x) { return x * fastrcp(1.0f + __expf(-x)); }
__device__ __forceinline__ unsigned short f2bf(float f) {
  unsigned u = __float_as_uint(f);
  u += 0x7fffu + ((u >> 16) & 1u);
  return (unsigned short)(u >> 16);
}
__device__ __forceinline__ float bf2f(unsigned u16) {
  return __uint_as_float(u16 << 16);
}
__device__ __forceinline__ uint2 pack4(float a, float b, float c, float d) {
  uint2 r;
#ifdef HAVE_PK_BF16
  bf16x2 lo = __builtin_amdgcn_cvt_pk_bf16_f32(a, b);
  bf16x2 hi = __builtin_amdgcn_cvt_pk_bf16_f32(c, d);
  r.x = __builtin_bit_cast(unsigned, lo);
  r.y = __builtin_bit_cast(unsigned, hi);
#else
  r.x = (unsigned)f2bf(a) | ((unsigned)f2bf(b) << 16);
  r.y = (unsigned)f2bf(c) | ((unsigned)f2bf(d) << 16);
#endif
  return r;
}

// write one element into MFMA-packed layout: wpack[slot][k][n]
__device__ __forceinline__ void store_packed(unsigned short* __restrict__ wp,
                                             int slot, int k, int n, float v) {
  const int ks = k >> 5, lhi = (k >> 3) & 3, j = k & 7;
  const int tile = n >> 4, llo = n & 15;
  const int lane = lhi * 16 + llo;
  wp[slot * 65536 + (((ks * 16 + tile) * 64 + lane) << 3) + j] = f2bf(v);
}

// ---------------- fused precompute kernel ----------------
// [0,256) fold Mr/Ma (2 rows/block, writes wpack slots 0/1 packed) ; [256] cvec ;
// [257,321) gvec ; [321,577) Wqk = wq@wk^T (writes slot 4 packed) ;
// [577,961) mm_rows4 (4 rows/block) ; [961,1473) pack int_w2 (slot 2) / wg (slot 3)

__global__ void prep_kernel(
    const float* __restrict__ H, const float* __restrict__ wl,
    const float* __restrict__ wr, const float* __restrict__ int_w1,
    const float* __restrict__ res_w2, const float* __restrict__ atom_w2,
    const float* __restrict__ res_b2, const float* __restrict__ atom_b2,
    const float* __restrict__ int_b1, const float* __restrict__ simw,
    const float* __restrict__ wq_b, const float* __restrict__ wk_w,
    const float* __restrict__ wq_w, const float* __restrict__ int_w2,
    const float* __restrict__ wg_w,
    float* __restrict__ Hpl, float* __restrict__ Her,
    float* __restrict__ P1, float* __restrict__ P2,
    float* __restrict__ cvec, float* __restrict__ gv,
    unsigned short* __restrict__ wpack) {
  __shared__ float sbuf[1024];
  const int b = blockIdx.x, t = threadIdx.x;
  if (b < 256) {
    const bool isMa = b >= 128;
    const int i0 = (b & 127) * 2;
    const float wmix = 1.0f / (1.0f + __expf(-simw[0]));
    const float sc = isMa ? (1.0f - wmix) : wmix;
    const float* W2 = isMa ? atom_w2 : res_w2;
    sbuf[t] = W2[i0 * 256 + t];
    sbuf[256 + t] = W2[(i0 + 1) * 256 + t];
    __syncthreads();
    float a0 = 0.f, a1 = 0.f;
#pragma unroll 8
    for (int k = 0; k < 256; ++k) {
      const float w = int_w1[(512 + k) * 256 + t];
      a0 = fmaf(sbuf[k], w, a0);
      a1 = fmaf(sbuf[256 + k], w, a1);
    }
    const int slot = isMa ? 1 : 0;
    store_packed(wpack, slot, i0, t, a0 * sc);
    store_packed(wpack, slot, i0 + 1, t, a1 * sc);
  } else if (b == 256) {
    const float wmix = 1.0f / (1.0f + __expf(-simw[0]));
    float acc = int_b1[t];
#pragma unroll 8
    for (int k = 0; k < 256; ++k) {
      float bm = wmix * res_b2[k] + (1.0f - wmix) * atom_b2[k];
      acc += bm * int_w1[(512 + k) * 256 + t];
    }
    cvec[t] = acc;
  } else if (b < 321) {
    const int lane = t & 63, w = t >> 6;
    const int d = (b - 257) * 4 + w;
    float acc = 0.f;
#pragma unroll
    for (int i = 0; i < 4; ++i) {
      const int c = i * 64 + lane;
      acc += wk_w[d * 256 + c] * wq_b[c];
    }
    acc += __shfl_xor(acc, 1);
    acc += __shfl_xor(acc, 2);
    acc += __shfl_xor(acc, 4);
    acc += __shfl_xor(acc, 8);
    acc += __shfl_xor(acc, 16);
    acc += __shfl_xor(acc, 32);
    if (lane == 0) gv[d] = acc;
  } else if (b < 577) {
    const int r = b - 321;
    sbuf[t] = wq_w[r * 256 + t];
    __syncthreads();
    const float* wkrow = wk_w + t * 256;
    float a0 = 0.f, a1 = 0.f, a2 = 0.f, a3 = 0.f;
#pragma unroll 4
    for (int k = 0; k < 256; k += 4) {
      const f32x4 wv4 = *reinterpret_cast<const f32x4*>(&wkrow[k]);
      a0 = fmaf(sbuf[k + 0], wv4[0], a0);
      a1 = fmaf(sbuf[k + 1], wv4[1], a1);
      a2 = fmaf(sbuf[k + 2], wv4[2], a2);
      a3 = fmaf(sbuf[k + 3], wv4[3], a3);
    }
    store_packed(wpack, 4, r, t, (a0 + a1) + (a2 + a3));
  } else if (b < 961) {
    const int idx = b - 577;
    const int seg = idx / 96, r0 = (idx % 96) * 4;
    const float* A;
    const float* B;
    float* C;
    switch (seg) {
      case 0:  A = H + r0 * 256;            B = wl;              C = Hpl + r0 * 256; break;
      case 1:  A = H + (NPAR + r0) * 256;   B = wr;              C = Her + r0 * 256; break;
      case 2:  A = H + r0 * 256;            B = int_w1;          C = P1 + r0 * 256;  break;
      default: A = H + (NPAR + r0) * 256;   B = int_w1 + 65536;  C = P2 + r0 * 256;  break;
    }
#pragma unroll
    for (int j = 0; j < 4; ++j) sbuf[j * 256 + t] = A[j * 256 + t];
    __syncthreads();
    float a0 = 0.f, a1 = 0.f, a2 = 0.f, a3 = 0.f;
#pragma unroll 8
    for (int k = 0; k < 256; ++k) {
      const float bv = B[k * 256 + t];
      a0 = fmaf(sbuf[k], bv, a0);
      a1 = fmaf(sbuf[256 + k], bv, a1);
      a2 = fmaf(sbuf[512 + k], bv, a2);
      a3 = fmaf(sbuf[768 + k], bv, a3);
    }
    C[t] = a0;
    C[256 + t] = a1;
    C[512 + t] = a2;
    C[768 + t] = a3;
  } else {
    // pack int_w2 -> slot 2, wg -> slot 3 (same indexing as old pack_kernel)
    const int idx = (b - 961) * 256 + t;       // 0 .. 2*65536-1
    const int m = idx >> 16;                   // 0 or 1
    const int r = idx & 65535;
    const int chunk = r >> 9;
    const int lane = (r >> 3) & 63;
    const int j = r & 7;
    const int k = (chunk >> 4) * 32 + (lane >> 4) * 8 + j;
    const int n = (chunk & 15) * 16 + (lane & 15);
    const float* src = (m == 0) ? int_w2 : wg_w;
    wpack[(2 + m) * 65536 + r] = f2bf(src[k * 256 + n]);
  }
}

// ---------------- shared GEMM helpers ----------------

__device__ __forceinline__ void zero_acc4(f32x4 (&acc)[4][4]) {
#pragma unroll
  for (int mt = 0; mt < 4; ++mt)
#pragma unroll
    for (int nt = 0; nt < 4; ++nt)
      acc[mt][nt] = (f32x4){0.f, 0.f, 0.f, 0.f};
}

// transposed-acc: mfma(Wfrag, ActFrag) -> acc^T[d][e]
__device__ __forceinline__ void gemm4(f32x4 (&acc)[4][4],
                                      const unsigned short* __restrict__ wp,
                                      const unsigned short* ub, int lane, int wv) {
  const int l15 = lane & 15, l4 = lane >> 4;
#pragma unroll
  for (int ks = 0; ks < 8; ++ks) {
    bf16x8 a[4];
#pragma unroll
    for (int mt = 0; mt < 4; ++mt)
      a[mt] = *reinterpret_cast<const bf16x8*>(wp + ((ks * 16 + wv * 4 + mt) * 64 + lane) * 8);
    __builtin_amdgcn_s_setprio(1);
#pragma unroll
    for (int nt = 0; nt < 4; ++nt) {
      bf16x8 b = *reinterpret_cast<const bf16x8*>(ub + (nt * 16 + l15) * 264 + ks * 32 + l4 * 8);
#pragma unroll
      for (int mt = 0; mt < 4; ++mt)
        acc[mt][nt] = __builtin_amdgcn_mfma_f32_16x16x32_bf16(a[mt], b, acc[mt][nt], 0, 0, 0);
    }
    __builtin_amdgcn_s_setprio(0);
  }
}

// fill ubuf[e][d] = silu(Sv[e]*w1[d] + b1[d])
__device__ __forceinline__ void fill_u(unsigned short* ub, const float* Sv,
                                       const float* __restrict__ w1,
                                       const float* __restrict__ b1, int t) {
  const int dg = t & 31, rb = t >> 5;
  const f32x4 w1a = *reinterpret_cast<const f32x4*>(&w1[dg * 8]);
  const f32x4 w1b = *reinterpret_cast<const f32x4*>(&w1[dg * 8 + 4]);
  const f32x4 b1a = *reinterpret_cast<const f32x4*>(&b1[dg * 8]);
  const f32x4 b1b = *reinterpret_cast<const f32x4*>(&b1[dg * 8 + 4]);
#pragma unroll
  for (int i = 0; i < 8; ++i) {
    const int e = rb + i * 8;
    const float s = Sv[e];
    uint2 lo = pack4(silu(fmaf(s, w1a[0], b1a[0])), silu(fmaf(s, w1a[1], b1a[1])),
                     silu(fmaf(s, w1a[2], b1a[2])), silu(fmaf(s, w1a[3], b1a[3])));
    uint2 hi = pack4(silu(fmaf(s, w1b[0], b1b[0])), silu(fmaf(s, w1b[1], b1b[1])),
                     silu(fmaf(s, w1b[2], b1b[2])), silu(fmaf(s, w1b[3], b1b[3])));
    uint4 pk = {lo.x, lo.y, hi.x, hi.y};
    *reinterpret_cast<uint4*>(&ub[e * 264 + dg * 8]) = pk;
  }
}

// ---------------- table build: tabF[n][d] = F(n*SDELTA)[d], fp32 out ----------------

__global__ __launch_bounds__(256, 3) void tab_kernel(
    const float* __restrict__ res_w1, const float* __restrict__ res_b1,
    const float* __restrict__ atom_w1, const float* __restrict__ atom_b1,
    const unsigned short* __restrict__ wpack, float* __restrict__ tabF) {
  __shared__ __align__(16) unsigned short ubuf[64 * 264];
  __shared__ float Sv[64];
  const int t = threadIdx.x, lane = t & 63, wv = t >> 6;
  const int l15 = lane & 15, l4 = lane >> 4;
  const int n0 = blockIdx.x * 64;
  if (t < 64) Sv[t] = (n0 + t) * SDELTA;
  __syncthreads();
  f32x4 acc[4][4];
  zero_acc4(acc);
  fill_u(ubuf, Sv, res_w1, res_b1, t);
  __syncthreads();
  gemm4(acc, wpack + 0 * 65536, ubuf, lane, wv);
  __syncthreads();
  fill_u(ubuf, Sv, atom_w1, atom_b1, t);
  __syncthreads();
  gemm4(acc, wpack + 1 * 65536, ubuf, lane, wv);
#pragma unroll
  for (int mt = 0; mt < 4; ++mt) {
    const int d = wv * 64 + mt * 16 + l4 * 4;
#pragma unroll
    for (int nt = 0; nt < 4; ++nt) {
      const int n = n0 + nt * 16 + l15;
      *reinterpret_cast<f32x4*>(&tabF[n * 256 + d]) = acc[mt][nt];
    }
  }
}

// ---------------- pairwise kernel (64-row tiles): fp32-table-interp h + 2 GEMMs -------
// Verified-best configuration (R7, 92 us): XCD-swizzled grid, Sv+pc in LDS,
// 264-stride ubuf, 256 threads, __launch_bounds__(256,4), VGPR 64.
// LEDGER: rcp ok(-7us) | persistent-grid BAD(10x FETCH) | LDS-shrink BAD(spill) |
// TLP-double BAD(R8: occupancy 2x but +9us, FETCH+conflicts up). Structural floor
// for this barrier-phase design; next lever would be producer-consumer waves.

__global__ __launch_bounds__(256, 4) void pair_kernel(
    const float* __restrict__ Xg, const float* __restrict__ tabF,
    const float* __restrict__ int_b2, const float* __restrict__ wg_b,
    const unsigned short* __restrict__ wpack, const float* __restrict__ cvec,
    const float* __restrict__ P1, const float* __restrict__ P2,
    const float* __restrict__ Hpl, const float* __restrict__ Her,
    float* __restrict__ ftri, unsigned short* __restrict__ Zsw) {
  __shared__ __align__(16) unsigned short ubuf[64 * 264];
  __shared__ float Sv[64];
  __shared__ float pc[DD];
  const int t = threadIdx.x, lane = t & 63, wv = t >> 6;
  const int l15 = lane & 15, l4 = lane >> 4;
  const int wg = (blockIdx.x & 7) * 288 + (blockIdx.x >> 3);  // bijective XCD swizzle
  const int p = wg / 6, cc = wg % 6, e0 = cc * 64;
  const int d0 = wv * 64;

  if (t < 64) {
    const int e = e0 + t;
    float dx = Xg[p * 42 + 3] - Xg[(NPAR + e) * 42 + 3];
    float dy = Xg[p * 42 + 4] - Xg[(NPAR + e) * 42 + 4];
    float dz = Xg[p * 42 + 5] - Xg[(NPAR + e) * 42 + 5];
    Sv[t] = dx * dx + dy * dy + dz * dz;
  }
  pc[t] = P1[p * DD + t] + cvec[t];
  __syncthreads();

  // h-fill: h[e][d] = silu(lerp(tabF, S[e])[d] + pc[d] + P2[e][d]) -> ubuf
  {
    const int dg = t & 31, rb = t >> 5;
    const f32x4 pca = *reinterpret_cast<const f32x4*>(&pc[dg * 8]);
    const f32x4 pcb = *reinterpret_cast<const f32x4*>(&pc[dg * 8 + 4]);
#pragma unroll
    for (int i = 0; i < 8; ++i) {
      const int e = rb + i * 8;
      float sv = Sv[e] * SINVD;
      int idx = (int)sv;
      idx = idx > (NTAB - 2) ? (NTAB - 2) : idx;
      const float fr = sv - (float)idx;
      const f32x4 t0a = *reinterpret_cast<const f32x4*>(&tabF[idx * 256 + dg * 8]);
      const f32x4 t0b = *reinterpret_cast<const f32x4*>(&tabF[idx * 256 + dg * 8 + 4]);
      const f32x4 t1a = *reinterpret_cast<const f32x4*>(&tabF[(idx + 1) * 256 + dg * 8]);
      const f32x4 t1b = *reinterpret_cast<const f32x4*>(&tabF[(idx + 1) * 256 + dg * 8 + 4]);
      const f32x4 p2a = *reinterpret_cast<const f32x4*>(&P2[(e0 + e) * DD + dg * 8]);
      const f32x4 p2b = *reinterpret_cast<const f32x4*>(&P2[(e0 + e) * DD + dg * 8 + 4]);
      float z0 = fmaf(fr, t1a[0] - t0a[0], t0a[0]) + pca[0] + p2a[0];
      float z1 = fmaf(fr, t1a[1] - t0a[1], t0a[1]) + pca[1] + p2a[1];
      float z2 = fmaf(fr, t1a[2] - t0a[2], t0a[2]) + pca[2] + p2a[2];
      float z3 = fmaf(fr, t1a[3] - t0a[3], t0a[3]) + pca[3] + p2a[3];
      float z4 = fmaf(fr, t1b[0] - t0b[0], t0b[0]) + pcb[0] + p2b[0];
      float z5 = fmaf(fr, t1b[1] - t0b[1], t0b[1]) + pcb[1] + p2b[1];
      float z6 = fmaf(fr, t1b[2] - t0b[2], t0b[2]) + pcb[2] + p2b[2];
      float z7 = fmaf(fr, t1b[3] - t0b[3], t0b[3]) + pcb[3] + p2b[3];
      uint2 lo = pack4(silu(z0), silu(z1), silu(z2), silu(z3));
      uint2 hi = pack4(silu(z4), silu(z5), silu(z6), silu(z7));
      uint4 pk = {lo.x, lo.y, hi.x, hi.y};
      *reinterpret_cast<uint4*>(&ubuf[e * 264 + dg * 8]) = pk;
    }
  }
  __syncthreads();

  // Z = h @ int_w2 + int_b2 -> ubuf
  f32x4 acc[4][4];
  zero_acc4(acc);
  gemm4(acc, wpack + 2 * 65536, ubuf, lane, wv);
  __syncthreads();
#pragma unroll
  for (int mt = 0; mt < 4; ++mt) {
    const int d = d0 + mt * 16 + l4 * 4;
    const f32x4 bb = *reinterpret_cast<const f32x4*>(&int_b2[d]);
#pragma unroll
    for (int nt = 0; nt < 4; ++nt) {
      const int e = nt * 16 + l15;
      *reinterpret_cast<uint2*>(&ubuf[e * 264 + d]) =
          pack4(acc[mt][nt][0] + bb[0], acc[mt][nt][1] + bb[1],
                acc[mt][nt][2] + bb[2], acc[mt][nt][3] + bb[3]);
    }
  }
  __syncthreads();

  // swizzled MFMA-fragment-order store: grp = cc*4 + wv, e = grp*16 + l15
  {
    unsigned short* Zd = Zsw + (size_t)p * 98304 + (size_t)(cc * 4 + wv) * 4096 + lane * 8;
#pragma unroll
    for (int ks = 0; ks < 8; ++ks) {
      *reinterpret_cast<uint4*>(Zd + ks * 512) =
          *reinterpret_cast<const uint4*>(&ubuf[(wv * 16 + l15) * 264 + ks * 32 + l4 * 8]);
    }
  }

  // gate: f_tri[d] += Hpl[p][d] * sum_e sigm(Z@wg + b) * Her[e][d]
  zero_acc4(acc);
  gemm4(acc, wpack + 3 * 65536, ubuf, lane, wv);
#pragma unroll
  for (int mt = 0; mt < 4; ++mt) {
    const int d = d0 + mt * 16 + l4 * 4;
    const f32x4 bb = *reinterpret_cast<const f32x4*>(&wg_b[d]);
    const f32x4 hl = *reinterpret_cast<const f32x4*>(&Hpl[p * DD + d]);
    f32x4 fs = (f32x4){0.f, 0.f, 0.f, 0.f};
#pragma unroll
    for (int nt = 0; nt < 4; ++nt) {
      const int e = e0 + nt * 16 + l15;
      const f32x4 hr = *reinterpret_cast<const f32x4*>(&Her[e * DD + d]);
#pragma unroll
      for (int r = 0; r < 4; ++r)
        fs[r] += sigm(acc[mt][nt][r] + bb[r]) * hr[r];
    }
#pragma unroll
    for (int r = 0; r < 4; ++r) {
      float v = fs[r] * hl[r];
      v += __shfl_xor(v, 1);
      v += __shfl_xor(v, 2);
      v += __shfl_xor(v, 4);
      v += __shfl_xor(v, 8);
      if (l15 == 0) atomicAdd(&ftri[p * DD + d + r], v);
    }
  }
}

// ---------------- fused attention kernel: block = (p, 32-row chunk) ----------------

__global__ __launch_bounds__(256, 4) void attn_kernel(
    const unsigned short* __restrict__ Zsw, const float* __restrict__ gv,
    const unsigned short* __restrict__ wpack, float* __restrict__ cbufg) {
  __shared__ __align__(16) unsigned short Tc[32 * 264];
  __shared__ float red[128];
  __shared__ float red2[128];
  const int t = threadIdx.x, lane = t & 63, wv = t >> 6;
  const int l15 = lane & 15, l4 = lane >> 4;
  const int xcd = blockIdx.x & 7, inner = blockIdx.x >> 3;
  const int p = (inner / 12) * 8 + xcd, c = inner % 12;
  const unsigned short* Zsp = Zsw + (size_t)p * 98304;
  const unsigned short* wqk = wpack + 4 * 65536;

  // T' = (Zc @ Wqk + gv) / 16 for 32 rows (groups 2c, 2c+1), double-buffered
  {
    f32x4 ta[4][2];
#pragma unroll
    for (int mt = 0; mt < 4; ++mt)
#pragma unroll
      for (int nt = 0; nt < 2; ++nt) ta[mt][nt] = (f32x4){0.f, 0.f, 0.f, 0.f};
    const unsigned short* Tb = Zsp + (size_t)(c * 2) * 4096 + lane * 8;
    bf16x8 bcur[2], bnxt[2];
#pragma unroll
    for (int nt = 0; nt < 2; ++nt)
      bcur[nt] = *reinterpret_cast<const bf16x8*>(Tb + nt * 4096);
#pragma unroll
    for (int ks = 0; ks < 8; ++ks) {
      if (ks < 7) {
#pragma unroll
        for (int nt = 0; nt < 2; ++nt)
          bnxt[nt] = *reinterpret_cast<const bf16x8*>(Tb + nt * 4096 + (ks + 1) * 512);
      }
      bf16x8 a[4];
#pragma unroll
      for (int mt = 0; mt < 4; ++mt)
        a[mt] = *reinterpret_cast<const bf16x8*>(wqk + ((ks * 16 + wv * 4 + mt) * 64 + lane) * 8);
      __builtin_amdgcn_s_setprio(1);
#pragma unroll
      for (int nt = 0; nt < 2; ++nt)
#pragma unroll
        for (int mt = 0; mt < 4; ++mt)
          ta[mt][nt] = __builtin_amdgcn_mfma_f32_16x16x32_bf16(a[mt], bcur[nt], ta[mt][nt], 0, 0, 0);
      __builtin_amdgcn_s_setprio(0);
      if (ks < 7) {
#pragma unroll
        for (int nt = 0; nt < 2; ++nt) bcur[nt] = bnxt[nt];
      }
    }
#pragma unroll
    for (int mt = 0; mt < 4; ++mt) {
      const int d = wv * 64 + mt * 16 + l4 * 4;
      const f32x4 gq = *reinterpret_cast<const f32x4*>(&gv[d]);
#pragma unroll
      for (int nt = 0; nt < 2; ++nt) {
        const int e = nt * 16 + l15;
        *reinterpret_cast<uint2*>(&Tc[e * 264 + d]) =
            pack4((ta[mt][nt][0] + gq[0]) * 0.0625f, (ta[mt][nt][1] + gq[1]) * 0.0625f,
                  (ta[mt][nt][2] + gq[2]) * 0.0625f, (ta[mt][nt][3] + gq[3]) * 0.0625f);
      }
    }
  }
  __syncthreads();

  // S = Tc @ Z^T; a-frags from LDS, b-frags 3+3 rolling prefetch
  f32x4 sc[2][6];
#pragma unroll
  for (int mt = 0; mt < 2; ++mt)
#pragma unroll
    for (int s = 0; s < 6; ++s) sc[mt][s] = (f32x4){0.f, 0.f, 0.f, 0.f};

  {
    const unsigned short* Sb = Zsp + (size_t)wv * 4096 + lane * 8;
    bf16x8 b0[3], b1[3];
#pragma unroll
    for (int j = 0; j < 3; ++j)
      b0[j] = *reinterpret_cast<const bf16x8*>(Sb + j * 16384);
#pragma unroll
    for (int ks = 0; ks < 8; ++ks) {
#pragma unroll
      for (int j = 0; j < 3; ++j)
        b1[j] = *reinterpret_cast<const bf16x8*>(Sb + (3 + j) * 16384 + ks * 512);
      bf16x8 a[2];
#pragma unroll
      for (int mt = 0; mt < 2; ++mt)
        a[mt] = *reinterpret_cast<const bf16x8*>(&Tc[(mt * 16 + l15) * 264 + ks * 32 + l4 * 8]);
      __builtin_amdgcn_s_setprio(1);
#pragma unroll
      for (int j = 0; j < 3; ++j)
#pragma unroll
        for (int mt = 0; mt < 2; ++mt)
          sc[mt][j] = __builtin_amdgcn_mfma_f32_16x16x32_bf16(a[mt], b0[j], sc[mt][j], 0, 0, 0);
      __builtin_amdgcn_s_setprio(0);
      if (ks < 7) {
#pragma unroll
        for (int j = 0; j < 3; ++j)
          b0[j] = *reinterpret_cast<const bf16x8*>(Sb + j * 16384 + (ks + 1) * 512);
      }
      __builtin_amdgcn_s_setprio(1);
#pragma unroll
      for (int j = 0; j < 3; ++j)
#pragma unroll
        for (int mt = 0; mt < 2; ++mt)
          sc[mt][3 + j] = __builtin_amdgcn_mfma_f32_16x16x32_bf16(a[mt], b1[j], sc[mt][3 + j], 0, 0, 0);
      __builtin_amdgcn_s_setprio(0);
    }
  }

  // softmax over f (384 cols), rows e = mt*16 + l4*4 + r (32 rows)
  float rmax[2][4];
#pragma unroll
  for (int mt = 0; mt < 2; ++mt) {
#pragma unroll
    for (int r = 0; r < 4; ++r) {
      float m = -1e30f;
#pragma unroll
      for (int s = 0; s < 6; ++s) m = fmaxf(m, sc[mt][s][r]);
      m = fmaxf(m, __shfl_xor(m, 1));
      m = fmaxf(m, __shfl_xor(m, 2));
      m = fmaxf(m, __shfl_xor(m, 4));
      m = fmaxf(m, __shfl_xor(m, 8));
      rmax[mt][r] = m;
    }
  }
  if (l15 == 0) {
#pragma unroll
    for (int mt = 0; mt < 2; ++mt)
#pragma unroll
      for (int r = 0; r < 4; ++r)
        red[wv * 32 + mt * 16 + l4 * 4 + r] = rmax[mt][r];
  }
  __syncthreads();
#pragma unroll
  for (int mt = 0; mt < 2; ++mt) {
#pragma unroll
    for (int r = 0; r < 4; ++r) {
      const int row = mt * 16 + l4 * 4 + r;
      rmax[mt][r] = fmaxf(fmaxf(red[row], red[32 + row]), fmaxf(red[64 + row], red[96 + row]));
    }
  }

  float rsum[2][4];
#pragma unroll
  for (int mt = 0; mt < 2; ++mt) {
#pragma unroll
    for (int r = 0; r < 4; ++r) {
      float sSum = 0.f;
#pragma unroll
      for (int s = 0; s < 6; ++s) {
        float e = __expf(sc[mt][s][r] - rmax[mt][r]);
        sc[mt][s][r] = e;
        sSum += e;
      }
      sSum += __shfl_xor(sSum, 1);
      sSum += __shfl_xor(sSum, 2);
      sSum += __shfl_xor(sSum, 4);
      sSum += __shfl_xor(sSum, 8);
      rsum[mt][r] = sSum;
    }
  }
  if (l15 == 0) {
#pragma unroll
    for (int mt = 0; mt < 2; ++mt)
#pragma unroll
      for (int r = 0; r < 4; ++r)
        red2[wv * 32 + mt * 16 + l4 * 4 + r] = rsum[mt][r];
  }
  __syncthreads();
  float rinv[2][4];
#pragma unroll
  for (int mt = 0; mt < 2; ++mt) {
#pragma unroll
    for (int r = 0; r < 4; ++r) {
      const int row = mt * 16 + l4 * 4 + r;
      rinv[mt][r] = fastrcp(red2[row] + red2[32 + row] + red2[64 + row] + red2[96 + row]);
    }
  }

  // column sums of A over this chunk's 32 rows -> cbufg
#pragma unroll
  for (int s = 0; s < 6; ++s) {
    float v = 0.f;
#pragma unroll
    for (int mt = 0; mt < 2; ++mt)
#pragma unroll
      for (int r = 0; r < 4; ++r)
        v += sc[mt][s][r] * rinv[mt][r];
    v += __shfl_xor(v, 16);
    v += __shfl_xor(v, 32);
    if (lane < 16)
      atomicAdd(&cbufg[p * NEPI + (s * 4 + wv) * 16 + lane], v);
  }
}

// ---------------- fused output kernel: u[p] over all 24 groups + final epilogue ------
// Replaces outa (1152 blocks, atomics into ubufg) + out2 (384 blocks): one 384-block
// kernel, u stays in LDS, ubufg roundtrip and one launch gap eliminated.

__global__ __launch_bounds__(256) void outf_kernel(
    const unsigned short* __restrict__ Zsw, const float* __restrict__ cbufg,
    const float* __restrict__ ftri, const float* __restrict__ wvw,
    const float* __restrict__ wvb, float* __restrict__ out) {
  __shared__ float cb[NEPI];
  __shared__ float part[16][257];
  __shared__ float u[DD];
  const int p = blockIdx.x;
  const int t = threadIdx.x;
  const int lane = t & 63, wv = t >> 6;
  const int l15 = lane & 15, l4 = lane >> 4;
  cb[t] = cbufg[p * NEPI + t];
  if (t < NEPI - 256) cb[256 + t] = cbufg[p * NEPI + 256 + t];
  __syncthreads();
  const unsigned short* Zsp = Zsw + (size_t)p * 98304;
  float a16[16];
#pragma unroll
  for (int j = 0; j < 16; ++j) a16[j] = 0.f;
  for (int grp = 0; grp < 24; ++grp) {
    const float w = cb[grp * 16 + l15];
    const uint4 z0 = *reinterpret_cast<const uint4*>(Zsp + grp * 4096 + wv * 512 + lane * 8);
    const uint4 z1 = *reinterpret_cast<const uint4*>(Zsp + grp * 4096 + (wv + 4) * 512 + lane * 8);
    a16[0] = fmaf(w, bf2f(z0.x & 0xffffu), a16[0]);
    a16[1] = fmaf(w, bf2f(z0.x >> 16), a16[1]);
    a16[2] = fmaf(w, bf2f(z0.y & 0xffffu), a16[2]);
    a16[3] = fmaf(w, bf2f(z0.y >> 16), a16[3]);
    a16[4] = fmaf(w, bf2f(z0.z & 0xffffu), a16[4]);
    a16[5] = fmaf(w, bf2f(z0.z >> 16), a16[5]);
    a16[6] = fmaf(w, bf2f(z0.w & 0xffffu), a16[6]);
    a16[7] = fmaf(w, bf2f(z0.w >> 16), a16[7]);
    a16[8]  = fmaf(w, bf2f(z1.x & 0xffffu), a16[8]);
    a16[9]  = fmaf(w, bf2f(z1.x >> 16), a16[9]);
    a16[10] = fmaf(w, bf2f(z1.y & 0xffffu), a16[10]);
    a16[11] = fmaf(w, bf2f(z1.y >> 16), a16[11]);
    a16[12] = fmaf(w, bf2f(z1.z & 0xffffu), a16[12]);
    a16[13] = fmaf(w, bf2f(z1.z >> 16), a16[13]);
    a16[14] = fmaf(w, bf2f(z1.w & 0xffffu), a16[14]);
    a16[15] = fmaf(w, bf2f(z1.w >> 16), a16[15]);
  }
#pragma unroll
  for (int j = 0; j < 8; ++j) part[l15][wv * 32 + l4 * 8 + j] = a16[j];
#pragma unroll
  for (int j = 0; j < 8; ++j) part[l15][128 + wv * 32 + l4 * 8 + j] = a16[8 + j];
  __syncthreads();
  float uu = 0.f;
#pragma unroll
  for (int g = 0; g < 16; ++g) uu += part[g][t];
  u[t] = uu;
  __syncthreads();
  float acc = ftri[p * DD + t] + 384.0f * wvb[t];
#pragma unroll 8
  for (int d = 0; d < DD; ++d)
    acc = fmaf(u[d], wvw[d * DD + t], acc);
  out[p * DD + t] = acc * (1.0f / 384.0f);
}

// ---------------- launch ----------------

extern "C" void kernel_launch(void* const* d_in, const int* in_sizes, int n_in,
                              void* d_out, int out_size, void* d_ws, size_t ws_size,
                              hipStream_t stream) {
  (void)in_sizes; (void)n_in; (void)out_size; (void)ws_size;
  const float* H = (const float*)d_in[0];
  const float* X = (const float*)d_in[1];
  const float* res_w1 = (const float*)d_in[4];
  const float* res_b1 = (const float*)d_in[5];
  const float* res_w2 = (const float*)d_in[6];
  const float* res_b2 = (const float*)d_in[7];
  const float* atom_w1 = (const float*)d_in[8];
  const float* atom_b1 = (const float*)d_in[9];
  const float* atom_w2 = (const float*)d_in[10];
  const float* atom_b2 = (const float*)d_in[11];
  const float* simw = (const float*)d_in[12];
  const float* int_w1 = (const float*)d_in[13];
  const float* int_b1 = (const float*)d_in[14];
  const float* int_w2 = (const float*)d_in[15];
  const float* int_b2 = (const float*)d_in[16];
  const float* wl = (const float*)d_in[17];
  const float* wr = (const float*)d_in[18];
  const float* wg_w = (const float*)d_in[19];
  const float* wg_b = (const float*)d_in[20];
  const float* wq_w = (const float*)d_in[21];
  const float* wq_b = (const float*)d_in[22];
  const float* wk_w = (const float*)d_in[23];
  const float* wv_w = (const float*)d_in[25];
  const float* wv_b = (const float*)d_in[26];

  char* ws = (char*)d_ws;
  unsigned short* wpack = (unsigned short*)(ws + 0);      //  655360 B (5 slots)
  float* cvec  = (float*)(ws + 655360);                   //    1024 B
  float* gv    = (float*)(ws + 656384);                   //    1024 B
  float* P1    = (float*)(ws + 657408);                   //  393216 B
  float* P2    = (float*)(ws + 1050624);                  //  393216 B
  float* Hpl   = (float*)(ws + 1443840);                  //  393216 B
  float* Her   = (float*)(ws + 1837056);                  //  393216 B
  float* ftri  = (float*)(ws + 2230272);                  //  393216 B
  float* cbufg = (float*)(ws + 2623488);                  //  589824 B
  unsigned short* Zsw = (unsigned short*)(ws + 3606528);  // 75497472 B
  float* tabF  = (float*)(ws + 79104000);                 //  4194304 B (NTAB x 256 fp32)

  // independent of all kernels: overlap the H-tail copy with the kernel chain
  hipMemcpyAsync((float*)d_out + NPAR * DD, H + NPAR * DD,
                 (1024 - NPAR) * DD * sizeof(float), hipMemcpyDeviceToDevice, stream);
  hipMemsetAsync(ftri, 0, 393216 + 589824, stream);   // ftri + cbufg (ubufg gone)
  prep_kernel<<<1473, 256, 0, stream>>>(H, wl, wr, int_w1, res_w2, atom_w2,
                                        res_b2, atom_b2, int_b1, simw, wq_b, wk_w,
                                        wq_w, int_w2, wg_w,
                                        Hpl, Her, P1, P2, cvec, gv, wpack);
  tab_kernel<<<NTAB / 64, 256, 0, stream>>>(res_w1, res_b1, atom_w1, atom_b1, wpack, tabF);
  pair_kernel<<<2304, 256, 0, stream>>>(X, tabF, int_b2, wg_b, wpack, cvec,
                                        P1, P2, Hpl, Her, ftri, Zsw);
  attn_kernel<<<4608, 256, 0, stream>>>(Zsw, gv, wpack, cbufg);
  outf_kernel<<<384, 256, 0, stream>>>(Zsw, cbufg, ftri, wv_w, wv_b, (float*)d_out);
}

// Round 10
// 306.626 us; speedup vs baseline: 1.0611x; 1.0022x over previous
//
#include <hip/hip_runtime.h>

#define NPAR 384
#define NEPI 384
#define DD   256
#define NTAB 4096
#define SMAX 96.0f
#define SDELTA (SMAX / NTAB)
#define SINVD (NTAB / SMAX)

using bf16x8 = __bf16 __attribute__((ext_vector_type(8)));
using bf16x2 = __bf16 __attribute__((ext_vector_type(2)));
using f32x4  = float __attribute__((ext_vector_type(4)));

#if defined(__has_builtin)
#if __has_builtin(__builtin_amdgcn_cvt_pk_bf16_f32)
#define HAVE_PK_BF16 1
#endif
#if __has_builtin(__builtin_amdgcn_rcpf)
#define HAVE_RCPF 1
#endif
#endif

__device__ __forceinline__ float fastrcp(float x) {
#ifdef HAVE_RCPF
  return __builtin_amdgcn_rcpf(x);   // v_rcp_f32, ~1 ulp — plenty for bf16 outputs
#else
  return 1.0f / x;
#endif
}
__device__ __forceinline__ float sigm(float x) { return fastrcp(1.0f + __expf(-x)); }
__device__ __forceinline__ float silu(float x) { return x * fastrcp(1.0f + __expf(-x)); }
__device__ __forceinline__ unsigned short f2bf(float f) {
  unsigned u = __float_as_uint(f);
  u += 0x7fffu + ((u >> 16) & 1u);
  return (unsigned short)(u >> 16);
}
__device__ __forceinline__ float bf2f(unsigned u16) {
  return __uint_as_float(u16 << 16);
}
__device__ __forceinline__ uint2 pack4(float a, float b, float c, float d) {
  uint2 r;
#ifdef HAVE_PK_BF16
  bf16x2 lo = __builtin_amdgcn_cvt_pk_bf16_f32(a, b);
  bf16x2 hi = __builtin_amdgcn_cvt_pk_bf16_f32(c, d);
  r.x = __builtin_bit_cast(unsigned, lo);
  r.y = __builtin_bit_cast(unsigned, hi);
#else
  r.x = (unsigned)f2bf(a) | ((unsigned)f2bf(b) << 16);
  r.y = (unsigned)f2bf(c) | ((unsigned)f2bf(d) << 16);
#endif
  return r;
}

// write one element into MFMA-packed layout: wpack[slot][k][n]
__device__ __forceinline__ void store_packed(unsigned short* __restrict__ wp,
                                             int slot, int k, int n, float v) {
  const int ks = k >> 5, lhi = (k >> 3) & 3, j = k & 7;
  const int tile = n >> 4, llo = n & 15;
  const int lane = lhi * 16 + llo;
  wp[slot * 65536 + (((ks * 16 + tile) * 64 + lane) << 3) + j] = f2bf(v);
}

// ---------------- fused precompute kernel ----------------
// [0,256) fold Mr/Ma (2 rows/block, writes wpack slots 0/1 packed) ; [256] cvec ;
// [257,321) gvec ; [321,577) Wqk = wq@wk^T (writes slot 4 packed) ;
// [577,961) mm_rows4 (4 rows/block) ; [961,1473) pack int_w2 (slot 2) / wg (slot 3)

__global__ void prep_kernel(
    const float* __restrict__ H, const float* __restrict__ wl,
    const float* __restrict__ wr, const float* __restrict__ int_w1,
    const float* __restrict__ res_w2, const float* __restrict__ atom_w2,
    const float* __restrict__ res_b2, const float* __restrict__ atom_b2,
    const float* __restrict__ int_b1, const float* __restrict__ simw,
    const float* __restrict__ wq_b, const float* __restrict__ wk_w,
    const float* __restrict__ wq_w, const float* __restrict__ int_w2,
    const float* __restrict__ wg_w,
    float* __restrict__ Hpl, float* __restrict__ Her,
    float* __restrict__ P1, float* __restrict__ P2,
    float* __restrict__ cvec, float* __restrict__ gv,
    unsigned short* __restrict__ wpack) {
  __shared__ float sbuf[1024];
  const int b = blockIdx.x, t = threadIdx.x;
  if (b < 256) {
    const bool isMa = b >= 128;
    const int i0 = (b & 127) * 2;
    const float wmix = 1.0f / (1.0f + __expf(-simw[0]));
    const float sc = isMa ? (1.0f - wmix) : wmix;
    const float* W2 = isMa ? atom_w2 : res_w2;
    sbuf[t] = W2[i0 * 256 + t];
    sbuf[256 + t] = W2[(i0 + 1) * 256 + t];
    __syncthreads();
    float a0 = 0.f, a1 = 0.f;
#pragma unroll 8
    for (int k = 0; k < 256; ++k) {
      const float w = int_w1[(512 + k) * 256 + t];
      a0 = fmaf(sbuf[k], w, a0);
      a1 = fmaf(sbuf[256 + k], w, a1);
    }
    const int slot = isMa ? 1 : 0;
    store_packed(wpack, slot, i0, t, a0 * sc);
    store_packed(wpack, slot, i0 + 1, t, a1 * sc);
  } else if (b == 256) {
    const float wmix = 1.0f / (1.0f + __expf(-simw[0]));
    float acc = int_b1[t];
#pragma unroll 8
    for (int k = 0; k < 256; ++k) {
      float bm = wmix * res_b2[k] + (1.0f - wmix) * atom_b2[k];
      acc += bm * int_w1[(512 + k) * 256 + t];
    }
    cvec[t] = acc;
  } else if (b < 321) {
    const int lane = t & 63, w = t >> 6;
    const int d = (b - 257) * 4 + w;
    float acc = 0.f;
#pragma unroll
    for (int i = 0; i < 4; ++i) {
      const int c = i * 64 + lane;
      acc += wk_w[d * 256 + c] * wq_b[c];
    }
    acc += __shfl_xor(acc, 1);
    acc += __shfl_xor(acc, 2);
    acc += __shfl_xor(acc, 4);
    acc += __shfl_xor(acc, 8);
    acc += __shfl_xor(acc, 16);
    acc += __shfl_xor(acc, 32);
    if (lane == 0) gv[d] = acc;
  } else if (b < 577) {
    const int r = b - 321;
    sbuf[t] = wq_w[r * 256 + t];
    __syncthreads();
    const float* wkrow = wk_w + t * 256;
    float a0 = 0.f, a1 = 0.f, a2 = 0.f, a3 = 0.f;
#pragma unroll 4
    for (int k = 0; k < 256; k += 4) {
      const f32x4 wv4 = *reinterpret_cast<const f32x4*>(&wkrow[k]);
      a0 = fmaf(sbuf[k + 0], wv4[0], a0);
      a1 = fmaf(sbuf[k + 1], wv4[1], a1);
      a2 = fmaf(sbuf[k + 2], wv4[2], a2);
      a3 = fmaf(sbuf[k + 3], wv4[3], a3);
    }
    store_packed(wpack, 4, r, t, (a0 + a1) + (a2 + a3));
  } else if (b < 961) {
    const int idx = b - 577;
    const int seg = idx / 96, r0 = (idx % 96) * 4;
    const float* A;
    const float* B;
    float* C;
    switch (seg) {
      case 0:  A = H + r0 * 256;            B = wl;              C = Hpl + r0 * 256; break;
      case 1:  A = H + (NPAR + r0) * 256;   B = wr;              C = Her + r0 * 256; break;
      case 2:  A = H + r0 * 256;            B = int_w1;          C = P1 + r0 * 256;  break;
      default: A = H + (NPAR + r0) * 256;   B = int_w1 + 65536;  C = P2 + r0 * 256;  break;
    }
#pragma unroll
    for (int j = 0; j < 4; ++j) sbuf[j * 256 + t] = A[j * 256 + t];
    __syncthreads();
    float a0 = 0.f, a1 = 0.f, a2 = 0.f, a3 = 0.f;
#pragma unroll 8
    for (int k = 0; k < 256; ++k) {
      const float bv = B[k * 256 + t];
      a0 = fmaf(sbuf[k], bv, a0);
      a1 = fmaf(sbuf[256 + k], bv, a1);
      a2 = fmaf(sbuf[512 + k], bv, a2);
      a3 = fmaf(sbuf[768 + k], bv, a3);
    }
    C[t] = a0;
    C[256 + t] = a1;
    C[512 + t] = a2;
    C[768 + t] = a3;
  } else {
    // pack int_w2 -> slot 2, wg -> slot 3 (same indexing as old pack_kernel)
    const int idx = (b - 961) * 256 + t;       // 0 .. 2*65536-1
    const int m = idx >> 16;                   // 0 or 1
    const int r = idx & 65535;
    const int chunk = r >> 9;
    const int lane = (r >> 3) & 63;
    const int j = r & 7;
    const int k = (chunk >> 4) * 32 + (lane >> 4) * 8 + j;
    const int n = (chunk & 15) * 16 + (lane & 15);
    const float* src = (m == 0) ? int_w2 : wg_w;
    wpack[(2 + m) * 65536 + r] = f2bf(src[k * 256 + n]);
  }
}

// ---------------- shared GEMM helpers ----------------

__device__ __forceinline__ void zero_acc4(f32x4 (&acc)[4][4]) {
#pragma unroll
  for (int mt = 0; mt < 4; ++mt)
#pragma unroll
    for (int nt = 0; nt < 4; ++nt)
      acc[mt][nt] = (f32x4){0.f, 0.f, 0.f, 0.f};
}

// transposed-acc: mfma(Wfrag, ActFrag) -> acc^T[d][e]
__device__ __forceinline__ void gemm4(f32x4 (&acc)[4][4],
                                      const unsigned short* __restrict__ wp,
                                      const unsigned short* ub, int lane, int wv) {
  const int l15 = lane & 15, l4 = lane >> 4;
#pragma unroll
  for (int ks = 0; ks < 8; ++ks) {
    bf16x8 a[4];
#pragma unroll
    for (int mt = 0; mt < 4; ++mt)
      a[mt] = *reinterpret_cast<const bf16x8*>(wp + ((ks * 16 + wv * 4 + mt) * 64 + lane) * 8);
    __builtin_amdgcn_s_setprio(1);
#pragma unroll
    for (int nt = 0; nt < 4; ++nt) {
      bf16x8 b = *reinterpret_cast<const bf16x8*>(ub + (nt * 16 + l15) * 264 + ks * 32 + l4 * 8);
#pragma unroll
      for (int mt = 0; mt < 4; ++mt)
        acc[mt][nt] = __builtin_amdgcn_mfma_f32_16x16x32_bf16(a[mt], b, acc[mt][nt], 0, 0, 0);
    }
    __builtin_amdgcn_s_setprio(0);
  }
}

// fill ubuf[e][d] = silu(Sv[e]*w1[d] + b1[d])
__device__ __forceinline__ void fill_u(unsigned short* ub, const float* Sv,
                                       const float* __restrict__ w1,
                                       const float* __restrict__ b1, int t) {
  const int dg = t & 31, rb = t >> 5;
  const f32x4 w1a = *reinterpret_cast<const f32x4*>(&w1[dg * 8]);
  const f32x4 w1b = *reinterpret_cast<const f32x4*>(&w1[dg * 8 + 4]);
  const f32x4 b1a = *reinterpret_cast<const f32x4*>(&b1[dg * 8]);
  const f32x4 b1b = *reinterpret_cast<const f32x4*>(&b1[dg * 8 + 4]);
#pragma unroll
  for (int i = 0; i < 8; ++i) {
    const int e = rb + i * 8;
    const float s = Sv[e];
    uint2 lo = pack4(silu(fmaf(s, w1a[0], b1a[0])), silu(fmaf(s, w1a[1], b1a[1])),
                     silu(fmaf(s, w1a[2], b1a[2])), silu(fmaf(s, w1a[3], b1a[3])));
    uint2 hi = pack4(silu(fmaf(s, w1b[0], b1b[0])), silu(fmaf(s, w1b[1], b1b[1])),
                     silu(fmaf(s, w1b[2], b1b[2])), silu(fmaf(s, w1b[3], b1b[3])));
    uint4 pk = {lo.x, lo.y, hi.x, hi.y};
    *reinterpret_cast<uint4*>(&ub[e * 264 + dg * 8]) = pk;
  }
}

// ---------------- table build: tabF[n][d] = F(n*SDELTA)[d], fp32 out ----------------

__global__ __launch_bounds__(256, 3) void tab_kernel(
    const float* __restrict__ res_w1, const float* __restrict__ res_b1,
    const float* __restrict__ atom_w1, const float* __restrict__ atom_b1,
    const unsigned short* __restrict__ wpack, float* __restrict__ tabF) {
  __shared__ __align__(16) unsigned short ubuf[64 * 264];
  __shared__ float Sv[64];
  const int t = threadIdx.x, lane = t & 63, wv = t >> 6;
  const int l15 = lane & 15, l4 = lane >> 4;
  const int n0 = blockIdx.x * 64;
  if (t < 64) Sv[t] = (n0 + t) * SDELTA;
  __syncthreads();
  f32x4 acc[4][4];
  zero_acc4(acc);
  fill_u(ubuf, Sv, res_w1, res_b1, t);
  __syncthreads();
  gemm4(acc, wpack + 0 * 65536, ubuf, lane, wv);
  __syncthreads();
  fill_u(ubuf, Sv, atom_w1, atom_b1, t);
  __syncthreads();
  gemm4(acc, wpack + 1 * 65536, ubuf, lane, wv);
#pragma unroll
  for (int mt = 0; mt < 4; ++mt) {
    const int d = wv * 64 + mt * 16 + l4 * 4;
#pragma unroll
    for (int nt = 0; nt < 4; ++nt) {
      const int n = n0 + nt * 16 + l15;
      *reinterpret_cast<f32x4*>(&tabF[n * 256 + d]) = acc[mt][nt];
    }
  }
}

// ---------------- pairwise kernel (64-row tiles): fp32-table-interp h + 2 GEMMs -------
// Verified-best configuration (R7, 92 us): XCD-swizzled grid, Sv+pc in LDS,
// 264-stride ubuf, 256 threads, __launch_bounds__(256,4), VGPR 64.
// LEDGER: rcp ok(-7us) | persistent-grid BAD(10x FETCH) | LDS-shrink BAD(spill) |
// TLP-double BAD(R8) | structural floor for this barrier-phase design.

__global__ __launch_bounds__(256, 4) void pair_kernel(
    const float* __restrict__ Xg, const float* __restrict__ tabF,
    const float* __restrict__ int_b2, const float* __restrict__ wg_b,
    const unsigned short* __restrict__ wpack, const float* __restrict__ cvec,
    const float* __restrict__ P1, const float* __restrict__ P2,
    const float* __restrict__ Hpl, const float* __restrict__ Her,
    float* __restrict__ ftri, unsigned short* __restrict__ Zsw) {
  __shared__ __align__(16) unsigned short ubuf[64 * 264];
  __shared__ float Sv[64];
  __shared__ float pc[DD];
  const int t = threadIdx.x, lane = t & 63, wv = t >> 6;
  const int l15 = lane & 15, l4 = lane >> 4;
  const int wg = (blockIdx.x & 7) * 288 + (blockIdx.x >> 3);  // bijective XCD swizzle
  const int p = wg / 6, cc = wg % 6, e0 = cc * 64;
  const int d0 = wv * 64;

  if (t < 64) {
    const int e = e0 + t;
    float dx = Xg[p * 42 + 3] - Xg[(NPAR + e) * 42 + 3];
    float dy = Xg[p * 42 + 4] - Xg[(NPAR + e) * 42 + 4];
    float dz = Xg[p * 42 + 5] - Xg[(NPAR + e) * 42 + 5];
    Sv[t] = dx * dx + dy * dy + dz * dz;
  }
  pc[t] = P1[p * DD + t] + cvec[t];
  __syncthreads();

  // h-fill: h[e][d] = silu(lerp(tabF, S[e])[d] + pc[d] + P2[e][d]) -> ubuf
  {
    const int dg = t & 31, rb = t >> 5;
    const f32x4 pca = *reinterpret_cast<const f32x4*>(&pc[dg * 8]);
    const f32x4 pcb = *reinterpret_cast<const f32x4*>(&pc[dg * 8 + 4]);
#pragma unroll
    for (int i = 0; i < 8; ++i) {
      const int e = rb + i * 8;
      float sv = Sv[e] * SINVD;
      int idx = (int)sv;
      idx = idx > (NTAB - 2) ? (NTAB - 2) : idx;
      const float fr = sv - (float)idx;
      const f32x4 t0a = *reinterpret_cast<const f32x4*>(&tabF[idx * 256 + dg * 8]);
      const f32x4 t0b = *reinterpret_cast<const f32x4*>(&tabF[idx * 256 + dg * 8 + 4]);
      const f32x4 t1a = *reinterpret_cast<const f32x4*>(&tabF[(idx + 1) * 256 + dg * 8]);
      const f32x4 t1b = *reinterpret_cast<const f32x4*>(&tabF[(idx + 1) * 256 + dg * 8 + 4]);
      const f32x4 p2a = *reinterpret_cast<const f32x4*>(&P2[(e0 + e) * DD + dg * 8]);
      const f32x4 p2b = *reinterpret_cast<const f32x4*>(&P2[(e0 + e) * DD + dg * 8 + 4]);
      float z0 = fmaf(fr, t1a[0] - t0a[0], t0a[0]) + pca[0] + p2a[0];
      float z1 = fmaf(fr, t1a[1] - t0a[1], t0a[1]) + pca[1] + p2a[1];
      float z2 = fmaf(fr, t1a[2] - t0a[2], t0a[2]) + pca[2] + p2a[2];
      float z3 = fmaf(fr, t1a[3] - t0a[3], t0a[3]) + pca[3] + p2a[3];
      float z4 = fmaf(fr, t1b[0] - t0b[0], t0b[0]) + pcb[0] + p2b[0];
      float z5 = fmaf(fr, t1b[1] - t0b[1], t0b[1]) + pcb[1] + p2b[1];
      float z6 = fmaf(fr, t1b[2] - t0b[2], t0b[2]) + pcb[2] + p2b[2];
      float z7 = fmaf(fr, t1b[3] - t0b[3], t0b[3]) + pcb[3] + p2b[3];
      uint2 lo = pack4(silu(z0), silu(z1), silu(z2), silu(z3));
      uint2 hi = pack4(silu(z4), silu(z5), silu(z6), silu(z7));
      uint4 pk = {lo.x, lo.y, hi.x, hi.y};
      *reinterpret_cast<uint4*>(&ubuf[e * 264 + dg * 8]) = pk;
    }
  }
  __syncthreads();

  // Z = h @ int_w2 + int_b2 -> ubuf
  f32x4 acc[4][4];
  zero_acc4(acc);
  gemm4(acc, wpack + 2 * 65536, ubuf, lane, wv);
  __syncthreads();
#pragma unroll
  for (int mt = 0; mt < 4; ++mt) {
    const int d = d0 + mt * 16 + l4 * 4;
    const f32x4 bb = *reinterpret_cast<const f32x4*>(&int_b2[d]);
#pragma unroll
    for (int nt = 0; nt < 4; ++nt) {
      const int e = nt * 16 + l15;
      *reinterpret_cast<uint2*>(&ubuf[e * 264 + d]) =
          pack4(acc[mt][nt][0] + bb[0], acc[mt][nt][1] + bb[1],
                acc[mt][nt][2] + bb[2], acc[mt][nt][3] + bb[3]);
    }
  }
  __syncthreads();

  // swizzled MFMA-fragment-order store: grp = cc*4 + wv, e = grp*16 + l15
  {
    unsigned short* Zd = Zsw + (size_t)p * 98304 + (size_t)(cc * 4 + wv) * 4096 + lane * 8;
#pragma unroll
    for (int ks = 0; ks < 8; ++ks) {
      *reinterpret_cast<uint4*>(Zd + ks * 512) =
          *reinterpret_cast<const uint4*>(&ubuf[(wv * 16 + l15) * 264 + ks * 32 + l4 * 8]);
    }
  }

  // gate: f_tri[d] += Hpl[p][d] * sum_e sigm(Z@wg + b) * Her[e][d]
  zero_acc4(acc);
  gemm4(acc, wpack + 3 * 65536, ubuf, lane, wv);
#pragma unroll
  for (int mt = 0; mt < 4; ++mt) {
    const int d = d0 + mt * 16 + l4 * 4;
    const f32x4 bb = *reinterpret_cast<const f32x4*>(&wg_b[d]);
    const f32x4 hl = *reinterpret_cast<const f32x4*>(&Hpl[p * DD + d]);
    f32x4 fs = (f32x4){0.f, 0.f, 0.f, 0.f};
#pragma unroll
    for (int nt = 0; nt < 4; ++nt) {
      const int e = e0 + nt * 16 + l15;
      const f32x4 hr = *reinterpret_cast<const f32x4*>(&Her[e * DD + d]);
#pragma unroll
      for (int r = 0; r < 4; ++r)
        fs[r] += sigm(acc[mt][nt][r] + bb[r]) * hr[r];
    }
#pragma unroll
    for (int r = 0; r < 4; ++r) {
      float v = fs[r] * hl[r];
      v += __shfl_xor(v, 1);
      v += __shfl_xor(v, 2);
      v += __shfl_xor(v, 4);
      v += __shfl_xor(v, 8);
      if (l15 == 0) atomicAdd(&ftri[p * DD + d + r], v);
    }
  }
}

// ---------------- fused attention kernel: block = (p, 64-row chunk), 8 waves --------
// R10: 2304 blocks x 512 thr (was 4608 x 256). Wave (q=wv&3, h=wv>>2): T' for
// d-quarter q of row-half h; S for rows h*32.. x col-streams j*4+q. Per-wave
// register/prefetch structure IDENTICAL to the 32-row version; occupancy same
// (16 waves/CU). Halves per-launch Zsp re-reads (885->442 MB) and Wqk reads
// (590->295 MB) — tests the L2-BW-bound hypothesis for attn.

__global__ __launch_bounds__(512, 4) void attn_kernel(
    const unsigned short* __restrict__ Zsw, const float* __restrict__ gv,
    const unsigned short* __restrict__ wpack, float* __restrict__ cbufg) {
  __shared__ __align__(16) unsigned short Tc[64 * 264];
  __shared__ float red[256];
  __shared__ float red2[256];
  const int t = threadIdx.x, lane = t & 63, wv = t >> 6;   // wv 0..7
  const int q = wv & 3, h = wv >> 2;
  const int l15 = lane & 15, l4 = lane >> 4;
  const int xcd = blockIdx.x & 7, inner = blockIdx.x >> 3;  // 2304 = 8*288
  const int p = (inner / 6) * 8 + xcd, c = inner % 6;
  const unsigned short* Zsp = Zsw + (size_t)p * 98304;
  const unsigned short* wqk = wpack + 4 * 65536;

  // T' = (Zc @ Wqk + gv) / 16: rows h*32+{0..31} (groups c*4+h*2+nt), d-quarter q
  {
    f32x4 ta[4][2];
#pragma unroll
    for (int mt = 0; mt < 4; ++mt)
#pragma unroll
      for (int nt = 0; nt < 2; ++nt) ta[mt][nt] = (f32x4){0.f, 0.f, 0.f, 0.f};
    const unsigned short* Tb = Zsp + (size_t)(c * 4 + h * 2) * 4096 + lane * 8;
    bf16x8 bcur[2], bnxt[2];
#pragma unroll
    for (int nt = 0; nt < 2; ++nt)
      bcur[nt] = *reinterpret_cast<const bf16x8*>(Tb + nt * 4096);
#pragma unroll
    for (int ks = 0; ks < 8; ++ks) {
      if (ks < 7) {
#pragma unroll
        for (int nt = 0; nt < 2; ++nt)
          bnxt[nt] = *reinterpret_cast<const bf16x8*>(Tb + nt * 4096 + (ks + 1) * 512);
      }
      bf16x8 a[4];
#pragma unroll
      for (int mt = 0; mt < 4; ++mt)
        a[mt] = *reinterpret_cast<const bf16x8*>(wqk + ((ks * 16 + q * 4 + mt) * 64 + lane) * 8);
      __builtin_amdgcn_s_setprio(1);
#pragma unroll
      for (int nt = 0; nt < 2; ++nt)
#pragma unroll
        for (int mt = 0; mt < 4; ++mt)
          ta[mt][nt] = __builtin_amdgcn_mfma_f32_16x16x32_bf16(a[mt], bcur[nt], ta[mt][nt], 0, 0, 0);
      __builtin_amdgcn_s_setprio(0);
      if (ks < 7) {
#pragma unroll
        for (int nt = 0; nt < 2; ++nt) bcur[nt] = bnxt[nt];
      }
    }
#pragma unroll
    for (int mt = 0; mt < 4; ++mt) {
      const int d = q * 64 + mt * 16 + l4 * 4;
      const f32x4 gq = *reinterpret_cast<const f32x4*>(&gv[d]);
#pragma unroll
      for (int nt = 0; nt < 2; ++nt) {
        const int e = h * 32 + nt * 16 + l15;
        *reinterpret_cast<uint2*>(&Tc[e * 264 + d]) =
            pack4((ta[mt][nt][0] + gq[0]) * 0.0625f, (ta[mt][nt][1] + gq[1]) * 0.0625f,
                  (ta[mt][nt][2] + gq[2]) * 0.0625f, (ta[mt][nt][3] + gq[3]) * 0.0625f);
      }
    }
  }
  __syncthreads();

  // S = Tc @ Z^T; rows h*32.., col-streams j -> group j*4+q; 3+3 rolling prefetch
  f32x4 sc[2][6];
#pragma unroll
  for (int mt = 0; mt < 2; ++mt)
#pragma unroll
    for (int s = 0; s < 6; ++s) sc[mt][s] = (f32x4){0.f, 0.f, 0.f, 0.f};

  {
    const unsigned short* Sb = Zsp + (size_t)q * 4096 + lane * 8;
    bf16x8 b0[3], b1[3];
#pragma unroll
    for (int j = 0; j < 3; ++j)
      b0[j] = *reinterpret_cast<const bf16x8*>(Sb + j * 16384);
#pragma unroll
    for (int ks = 0; ks < 8; ++ks) {
#pragma unroll
      for (int j = 0; j < 3; ++j)
        b1[j] = *reinterpret_cast<const bf16x8*>(Sb + (3 + j) * 16384 + ks * 512);
      bf16x8 a[2];
#pragma unroll
      for (int mt = 0; mt < 2; ++mt)
        a[mt] = *reinterpret_cast<const bf16x8*>(&Tc[(h * 32 + mt * 16 + l15) * 264 + ks * 32 + l4 * 8]);
      __builtin_amdgcn_s_setprio(1);
#pragma unroll
      for (int j = 0; j < 3; ++j)
#pragma unroll
        for (int mt = 0; mt < 2; ++mt)
          sc[mt][j] = __builtin_amdgcn_mfma_f32_16x16x32_bf16(a[mt], b0[j], sc[mt][j], 0, 0, 0);
      __builtin_amdgcn_s_setprio(0);
      if (ks < 7) {
#pragma unroll
        for (int j = 0; j < 3; ++j)
          b0[j] = *reinterpret_cast<const bf16x8*>(Sb + j * 16384 + (ks + 1) * 512);
      }
      __builtin_amdgcn_s_setprio(1);
#pragma unroll
      for (int j = 0; j < 3; ++j)
#pragma unroll
        for (int mt = 0; mt < 2; ++mt)
          sc[mt][3 + j] = __builtin_amdgcn_mfma_f32_16x16x32_bf16(a[mt], b1[j], sc[mt][3 + j], 0, 0, 0);
      __builtin_amdgcn_s_setprio(0);
    }
  }

  // softmax over f (384 cols): rows row32 = mt*16+l4*4+r of row-half h;
  // cross-wave (4 q's) reduce via red[h*128 + q*32 + row32]
  float rmax[2][4];
#pragma unroll
  for (int mt = 0; mt < 2; ++mt) {
#pragma unroll
    for (int r = 0; r < 4; ++r) {
      float m = -1e30f;
#pragma unroll
      for (int s = 0; s < 6; ++s) m = fmaxf(m, sc[mt][s][r]);
      m = fmaxf(m, __shfl_xor(m, 1));
      m = fmaxf(m, __shfl_xor(m, 2));
      m = fmaxf(m, __shfl_xor(m, 4));
      m = fmaxf(m, __shfl_xor(m, 8));
      rmax[mt][r] = m;
    }
  }
  if (l15 == 0) {
#pragma unroll
    for (int mt = 0; mt < 2; ++mt)
#pragma unroll
      for (int r = 0; r < 4; ++r)
        red[h * 128 + q * 32 + mt * 16 + l4 * 4 + r] = rmax[mt][r];
  }
  __syncthreads();
#pragma unroll
  for (int mt = 0; mt < 2; ++mt) {
#pragma unroll
    for (int r = 0; r < 4; ++r) {
      const int base = h * 128 + mt * 16 + l4 * 4 + r;
      rmax[mt][r] = fmaxf(fmaxf(red[base], red[base + 32]),
                          fmaxf(red[base + 64], red[base + 96]));
    }
  }

  float rsum[2][4];
#pragma unroll
  for (int mt = 0; mt < 2; ++mt) {
#pragma unroll
    for (int r = 0; r < 4; ++r) {
      float sSum = 0.f;
#pragma unroll
      for (int s = 0; s < 6; ++s) {
        float e = __expf(sc[mt][s][r] - rmax[mt][r]);
        sc[mt][s][r] = e;
        sSum += e;
      }
      sSum += __shfl_xor(sSum, 1);
      sSum += __shfl_xor(sSum, 2);
      sSum += __shfl_xor(sSum, 4);
      sSum += __shfl_xor(sSum, 8);
      rsum[mt][r] = sSum;
    }
  }
  if (l15 == 0) {
#pragma unroll
    for (int mt = 0; mt < 2; ++mt)
#pragma unroll
      for (int r = 0; r < 4; ++r)
        red2[h * 128 + q * 32 + mt * 16 + l4 * 4 + r] = rsum[mt][r];
  }
  __syncthreads();
  float rinv[2][4];
#pragma unroll
  for (int mt = 0; mt < 2; ++mt) {
#pragma unroll
    for (int r = 0; r < 4; ++r) {
      const int base = h * 128 + mt * 16 + l4 * 4 + r;
      rinv[mt][r] = fastrcp(red2[base] + red2[base + 32] + red2[base + 64] + red2[base + 96]);
    }
  }

  // column sums of A over this wave's 32 rows -> cbufg (group s*4+q)
#pragma unroll
  for (int s = 0; s < 6; ++s) {
    float v = 0.f;
#pragma unroll
    for (int mt = 0; mt < 2; ++mt)
#pragma unroll
      for (int r = 0; r < 4; ++r)
        v += sc[mt][s][r] * rinv[mt][r];
    v += __shfl_xor(v, 16);
    v += __shfl_xor(v, 32);
    if (lane < 16)
      atomicAdd(&cbufg[p * NEPI + (s * 4 + q) * 16 + lane], v);
  }
}

// ---------------- fused output kernel: u[p] over all 24 groups + final epilogue ------

__global__ __launch_bounds__(256) void outf_kernel(
    const unsigned short* __restrict__ Zsw, const float* __restrict__ cbufg,
    const float* __restrict__ ftri, const float* __restrict__ wvw,
    const float* __restrict__ wvb, float* __restrict__ out) {
  __shared__ float cb[NEPI];
  __shared__ float part[16][257];
  __shared__ float u[DD];
  const int p = blockIdx.x;
  const int t = threadIdx.x;
  const int lane = t & 63, wv = t >> 6;
  const int l15 = lane & 15, l4 = lane >> 4;
  cb[t] = cbufg[p * NEPI + t];
  if (t < NEPI - 256) cb[256 + t] = cbufg[p * NEPI + 256 + t];
  __syncthreads();
  const unsigned short* Zsp = Zsw + (size_t)p * 98304;
  float a16[16];
#pragma unroll
  for (int j = 0; j < 16; ++j) a16[j] = 0.f;
  for (int grp = 0; grp < 24; ++grp) {
    const float w = cb[grp * 16 + l15];
    const uint4 z0 = *reinterpret_cast<const uint4*>(Zsp + grp * 4096 + wv * 512 + lane * 8);
    const uint4 z1 = *reinterpret_cast<const uint4*>(Zsp + grp * 4096 + (wv + 4) * 512 + lane * 8);
    a16[0] = fmaf(w, bf2f(z0.x & 0xffffu), a16[0]);
    a16[1] = fmaf(w, bf2f(z0.x >> 16), a16[1]);
    a16[2] = fmaf(w, bf2f(z0.y & 0xffffu), a16[2]);
    a16[3] = fmaf(w, bf2f(z0.y >> 16), a16[3]);
    a16[4] = fmaf(w, bf2f(z0.z & 0xffffu), a16[4]);
    a16[5] = fmaf(w, bf2f(z0.z >> 16), a16[5]);
    a16[6] = fmaf(w, bf2f(z0.w & 0xffffu), a16[6]);
    a16[7] = fmaf(w, bf2f(z0.w >> 16), a16[7]);
    a16[8]  = fmaf(w, bf2f(z1.x & 0xffffu), a16[8]);
    a16[9]  = fmaf(w, bf2f(z1.x >> 16), a16[9]);
    a16[10] = fmaf(w, bf2f(z1.y & 0xffffu), a16[10]);
    a16[11] = fmaf(w, bf2f(z1.y >> 16), a16[11]);
    a16[12] = fmaf(w, bf2f(z1.z & 0xffffu), a16[12]);
    a16[13] = fmaf(w, bf2f(z1.z >> 16), a16[13]);
    a16[14] = fmaf(w, bf2f(z1.w & 0xffffu), a16[14]);
    a16[15] = fmaf(w, bf2f(z1.w >> 16), a16[15]);
  }
#pragma unroll
  for (int j = 0; j < 8; ++j) part[l15][wv * 32 + l4 * 8 + j] = a16[j];
#pragma unroll
  for (int j = 0; j < 8; ++j) part[l15][128 + wv * 32 + l4 * 8 + j] = a16[8 + j];
  __syncthreads();
  float uu = 0.f;
#pragma unroll
  for (int g = 0; g < 16; ++g) uu += part[g][t];
  u[t] = uu;
  __syncthreads();
  float acc = ftri[p * DD + t] + 384.0f * wvb[t];
#pragma unroll 8
  for (int d = 0; d < DD; ++d)
    acc = fmaf(u[d], wvw[d * DD + t], acc);
  out[p * DD + t] = acc * (1.0f / 384.0f);
}

// ---------------- launch ----------------

extern "C" void kernel_launch(void* const* d_in, const int* in_sizes, int n_in,
                              void* d_out, int out_size, void* d_ws, size_t ws_size,
                              hipStream_t stream) {
  (void)in_sizes; (void)n_in; (void)out_size; (void)ws_size;
  const float* H = (const float*)d_in[0];
  const float* X = (const float*)d_in[1];
  const float* res_w1 = (const float*)d_in[4];
  const float* res_b1 = (const float*)d_in[5];
  const float* res_w2 = (const float*)d_in[6];
  const float* res_b2 = (const float*)d_in[7];
  const float* atom_w1 = (const float*)d_in[8];
  const float* atom_b1 = (const float*)d_in[9];
  const float* atom_w2 = (const float*)d_in[10];
  const float* atom_b2 = (const float*)d_in[11];
  const float* simw = (const float*)d_in[12];
  const float* int_w1 = (const float*)d_in[13];
  const float* int_b1 = (const float*)d_in[14];
  const float* int_w2 = (const float*)d_in[15];
  const float* int_b2 = (const float*)d_in[16];
  const float* wl = (const float*)d_in[17];
  const float* wr = (const float*)d_in[18];
  const float* wg_w = (const float*)d_in[19];
  const float* wg_b = (const float*)d_in[20];
  const float* wq_w = (const float*)d_in[21];
  const float* wq_b = (const float*)d_in[22];
  const float* wk_w = (const float*)d_in[23];
  const float* wv_w = (const float*)d_in[25];
  const float* wv_b = (const float*)d_in[26];

  char* ws = (char*)d_ws;
  unsigned short* wpack = (unsigned short*)(ws + 0);      //  655360 B (5 slots)
  float* cvec  = (float*)(ws + 655360);                   //    1024 B
  float* gv    = (float*)(ws + 656384);                   //    1024 B
  float* P1    = (float*)(ws + 657408);                   //  393216 B
  float* P2    = (float*)(ws + 1050624);                  //  393216 B
  float* Hpl   = (float*)(ws + 1443840);                  //  393216 B
  float* Her   = (float*)(ws + 1837056);                  //  393216 B
  float* ftri  = (float*)(ws + 2230272);                  //  393216 B
  float* cbufg = (float*)(ws + 2623488);                  //  589824 B
  unsigned short* Zsw = (unsigned short*)(ws + 3606528);  // 75497472 B
  float* tabF  = (float*)(ws + 79104000);                 //  4194304 B (NTAB x 256 fp32)

  // independent of all kernels: overlap the H-tail copy with the kernel chain
  hipMemcpyAsync((float*)d_out + NPAR * DD, H + NPAR * DD,
                 (1024 - NPAR) * DD * sizeof(float), hipMemcpyDeviceToDevice, stream);
  hipMemsetAsync(ftri, 0, 393216 + 589824, stream);   // ftri + cbufg
  prep_kernel<<<1473, 256, 0, stream>>>(H, wl, wr, int_w1, res_w2, atom_w2,
                                        res_b2, atom_b2, int_b1, simw, wq_b, wk_w,
                                        wq_w, int_w2, wg_w,
                                        Hpl, Her, P1, P2, cvec, gv, wpack);
  tab_kernel<<<NTAB / 64, 256, 0, stream>>>(res_w1, res_b1, atom_w1, atom_b1, wpack, tabF);
  pair_kernel<<<2304, 256, 0, stream>>>(X, tabF, int_b2, wg_b, wpack, cvec,
                                        P1, P2, Hpl, Her, ftri, Zsw);
  attn_kernel<<<2304, 512, 0, stream>>>(Zsw, gv, wpack, cbufg);
  outf_kernel<<<384, 256, 0, stream>>>(Zsw, cbufg, ftri, wv_w, wv_b, (float*)d_out);
}

// Round 11
// 304.953 us; speedup vs baseline: 1.0669x; 1.0055x over previous
//
#include <hip/hip_runtime.h>

#define NPAR 384
#define NEPI 384
#define DD   256
#define NTAB 4096
#define SMAX 96.0f
#define SDELTA (SMAX / NTAB)
#define SINVD (NTAB / SMAX)

using bf16x8 = __bf16 __attribute__((ext_vector_type(8)));
using bf16x2 = __bf16 __attribute__((ext_vector_type(2)));
using f32x4  = float __attribute__((ext_vector_type(4)));

#if defined(__has_builtin)
#if __has_builtin(__builtin_amdgcn_cvt_pk_bf16_f32)
#define HAVE_PK_BF16 1
#endif
#if __has_builtin(__builtin_amdgcn_rcpf)
#define HAVE_RCPF 1
#endif
#endif

__device__ __forceinline__ float fastrcp(float x) {
#ifdef HAVE_RCPF
  return __builtin_amdgcn_rcpf(x);   // v_rcp_f32, ~1 ulp — plenty for bf16 outputs
#else
  return 1.0f / x;
#endif
}
__device__ __forceinline__ float sigm(float x) { return fastrcp(1.0f + __expf(-x)); }
__device__ __forceinline__ float silu(float x) { return x * fastrcp(1.0f + __expf(-x)); }
__device__ __forceinline__ unsigned short f2bf(float f) {
  unsigned u = __float_as_uint(f);
  u += 0x7fffu + ((u >> 16) & 1u);
  return (unsigned short)(u >> 16);
}
__device__ __forceinline__ float bf2f(unsigned u16) {
  return __uint_as_float(u16 << 16);
}
__device__ __forceinline__ uint2 pack4(float a, float b, float c, float d) {
  uint2 r;
#ifdef HAVE_PK_BF16
  bf16x2 lo = __builtin_amdgcn_cvt_pk_bf16_f32(a, b);
  bf16x2 hi = __builtin_amdgcn_cvt_pk_bf16_f32(c, d);
  r.x = __builtin_bit_cast(unsigned, lo);
  r.y = __builtin_bit_cast(unsigned, hi);
#else
  r.x = (unsigned)f2bf(a) | ((unsigned)f2bf(b) << 16);
  r.y = (unsigned)f2bf(c) | ((unsigned)f2bf(d) << 16);
#endif
  return r;
}

// write one element into MFMA-packed layout: wpack[slot][k][n]
__device__ __forceinline__ void store_packed(unsigned short* __restrict__ wp,
                                             int slot, int k, int n, float v) {
  const int ks = k >> 5, lhi = (k >> 3) & 3, j = k & 7;
  const int tile = n >> 4, llo = n & 15;
  const int lane = lhi * 16 + llo;
  wp[slot * 65536 + (((ks * 16 + tile) * 64 + lane) << 3) + j] = f2bf(v);
}

// ---------------- fused precompute kernel ----------------
// [0,256) fold Mr/Ma (2 rows/block, writes wpack slots 0/1 packed) ; [256] cvec ;
// [257,321) gvec ; [321,577) Wqk = wq@wk^T (writes slot 4 packed) ;
// [577,961) mm_rows4 (4 rows/block) ; [961,1473) pack int_w2 (slot 2) / wg (slot 3)

__global__ void prep_kernel(
    const float* __restrict__ H, const float* __restrict__ wl,
    const float* __restrict__ wr, const float* __restrict__ int_w1,
    const float* __restrict__ res_w2, const float* __restrict__ atom_w2,
    const float* __restrict__ res_b2, const float* __restrict__ atom_b2,
    const float* __restrict__ int_b1, const float* __restrict__ simw,
    const float* __restrict__ wq_b, const float* __restrict__ wk_w,
    const float* __restrict__ wq_w, const float* __restrict__ int_w2,
    const float* __restrict__ wg_w,
    float* __restrict__ Hpl, float* __restrict__ Her,
    float* __restrict__ P1, float* __restrict__ P2,
    float* __restrict__ cvec, float* __restrict__ gv,
    unsigned short* __restrict__ wpack) {
  __shared__ float sbuf[1024];
  const int b = blockIdx.x, t = threadIdx.x;
  if (b < 256) {
    const bool isMa = b >= 128;
    const int i0 = (b & 127) * 2;
    const float wmix = 1.0f / (1.0f + __expf(-simw[0]));
    const float sc = isMa ? (1.0f - wmix) : wmix;
    const float* W2 = isMa ? atom_w2 : res_w2;
    sbuf[t] = W2[i0 * 256 + t];
    sbuf[256 + t] = W2[(i0 + 1) * 256 + t];
    __syncthreads();
    float a0 = 0.f, a1 = 0.f;
#pragma unroll 8
    for (int k = 0; k < 256; ++k) {
      const float w = int_w1[(512 + k) * 256 + t];
      a0 = fmaf(sbuf[k], w, a0);
      a1 = fmaf(sbuf[256 + k], w, a1);
    }
    const int slot = isMa ? 1 : 0;
    store_packed(wpack, slot, i0, t, a0 * sc);
    store_packed(wpack, slot, i0 + 1, t, a1 * sc);
  } else if (b == 256) {
    const float wmix = 1.0f / (1.0f + __expf(-simw[0]));
    float acc = int_b1[t];
#pragma unroll 8
    for (int k = 0; k < 256; ++k) {
      float bm = wmix * res_b2[k] + (1.0f - wmix) * atom_b2[k];
      acc += bm * int_w1[(512 + k) * 256 + t];
    }
    cvec[t] = acc;
  } else if (b < 321) {
    const int lane = t & 63, w = t >> 6;
    const int d = (b - 257) * 4 + w;
    float acc = 0.f;
#pragma unroll
    for (int i = 0; i < 4; ++i) {
      const int c = i * 64 + lane;
      acc += wk_w[d * 256 + c] * wq_b[c];
    }
    acc += __shfl_xor(acc, 1);
    acc += __shfl_xor(acc, 2);
    acc += __shfl_xor(acc, 4);
    acc += __shfl_xor(acc, 8);
    acc += __shfl_xor(acc, 16);
    acc += __shfl_xor(acc, 32);
    if (lane == 0) gv[d] = acc;
  } else if (b < 577) {
    const int r = b - 321;
    sbuf[t] = wq_w[r * 256 + t];
    __syncthreads();
    const float* wkrow = wk_w + t * 256;
    float a0 = 0.f, a1 = 0.f, a2 = 0.f, a3 = 0.f;
#pragma unroll 4
    for (int k = 0; k < 256; k += 4) {
      const f32x4 wv4 = *reinterpret_cast<const f32x4*>(&wkrow[k]);
      a0 = fmaf(sbuf[k + 0], wv4[0], a0);
      a1 = fmaf(sbuf[k + 1], wv4[1], a1);
      a2 = fmaf(sbuf[k + 2], wv4[2], a2);
      a3 = fmaf(sbuf[k + 3], wv4[3], a3);
    }
    store_packed(wpack, 4, r, t, (a0 + a1) + (a2 + a3));
  } else if (b < 961) {
    const int idx = b - 577;
    const int seg = idx / 96, r0 = (idx % 96) * 4;
    const float* A;
    const float* B;
    float* C;
    switch (seg) {
      case 0:  A = H + r0 * 256;            B = wl;              C = Hpl + r0 * 256; break;
      case 1:  A = H + (NPAR + r0) * 256;   B = wr;              C = Her + r0 * 256; break;
      case 2:  A = H + r0 * 256;            B = int_w1;          C = P1 + r0 * 256;  break;
      default: A = H + (NPAR + r0) * 256;   B = int_w1 + 65536;  C = P2 + r0 * 256;  break;
    }
#pragma unroll
    for (int j = 0; j < 4; ++j) sbuf[j * 256 + t] = A[j * 256 + t];
    __syncthreads();
    float a0 = 0.f, a1 = 0.f, a2 = 0.f, a3 = 0.f;
#pragma unroll 8
    for (int k = 0; k < 256; ++k) {
      const float bv = B[k * 256 + t];
      a0 = fmaf(sbuf[k], bv, a0);
      a1 = fmaf(sbuf[256 + k], bv, a1);
      a2 = fmaf(sbuf[512 + k], bv, a2);
      a3 = fmaf(sbuf[768 + k], bv, a3);
    }
    C[t] = a0;
    C[256 + t] = a1;
    C[512 + t] = a2;
    C[768 + t] = a3;
  } else {
    // pack int_w2 -> slot 2, wg -> slot 3 (same indexing as old pack_kernel)
    const int idx = (b - 961) * 256 + t;       // 0 .. 2*65536-1
    const int m = idx >> 16;                   // 0 or 1
    const int r = idx & 65535;
    const int chunk = r >> 9;
    const int lane = (r >> 3) & 63;
    const int j = r & 7;
    const int k = (chunk >> 4) * 32 + (lane >> 4) * 8 + j;
    const int n = (chunk & 15) * 16 + (lane & 15);
    const float* src = (m == 0) ? int_w2 : wg_w;
    wpack[(2 + m) * 65536 + r] = f2bf(src[k * 256 + n]);
  }
}

// ---------------- shared GEMM helpers ----------------

__device__ __forceinline__ void zero_acc4(f32x4 (&acc)[4][4]) {
#pragma unroll
  for (int mt = 0; mt < 4; ++mt)
#pragma unroll
    for (int nt = 0; nt < 4; ++nt)
      acc[mt][nt] = (f32x4){0.f, 0.f, 0.f, 0.f};
}

// transposed-acc: mfma(Wfrag, ActFrag) -> acc^T[d][e]
__device__ __forceinline__ void gemm4(f32x4 (&acc)[4][4],
                                      const unsigned short* __restrict__ wp,
                                      const unsigned short* ub, int lane, int wv) {
  const int l15 = lane & 15, l4 = lane >> 4;
#pragma unroll
  for (int ks = 0; ks < 8; ++ks) {
    bf16x8 a[4];
#pragma unroll
    for (int mt = 0; mt < 4; ++mt)
      a[mt] = *reinterpret_cast<const bf16x8*>(wp + ((ks * 16 + wv * 4 + mt) * 64 + lane) * 8);
    __builtin_amdgcn_s_setprio(1);
#pragma unroll
    for (int nt = 0; nt < 4; ++nt) {
      bf16x8 b = *reinterpret_cast<const bf16x8*>(ub + (nt * 16 + l15) * 264 + ks * 32 + l4 * 8);
#pragma unroll
      for (int mt = 0; mt < 4; ++mt)
        acc[mt][nt] = __builtin_amdgcn_mfma_f32_16x16x32_bf16(a[mt], b, acc[mt][nt], 0, 0, 0);
    }
    __builtin_amdgcn_s_setprio(0);
  }
}

// fill ubuf[e][d] = silu(Sv[e]*w1[d] + b1[d])
__device__ __forceinline__ void fill_u(unsigned short* ub, const float* Sv,
                                       const float* __restrict__ w1,
                                       const float* __restrict__ b1, int t) {
  const int dg = t & 31, rb = t >> 5;
  const f32x4 w1a = *reinterpret_cast<const f32x4*>(&w1[dg * 8]);
  const f32x4 w1b = *reinterpret_cast<const f32x4*>(&w1[dg * 8 + 4]);
  const f32x4 b1a = *reinterpret_cast<const f32x4*>(&b1[dg * 8]);
  const f32x4 b1b = *reinterpret_cast<const f32x4*>(&b1[dg * 8 + 4]);
#pragma unroll
  for (int i = 0; i < 8; ++i) {
    const int e = rb + i * 8;
    const float s = Sv[e];
    uint2 lo = pack4(silu(fmaf(s, w1a[0], b1a[0])), silu(fmaf(s, w1a[1], b1a[1])),
                     silu(fmaf(s, w1a[2], b1a[2])), silu(fmaf(s, w1a[3], b1a[3])));
    uint2 hi = pack4(silu(fmaf(s, w1b[0], b1b[0])), silu(fmaf(s, w1b[1], b1b[1])),
                     silu(fmaf(s, w1b[2], b1b[2])), silu(fmaf(s, w1b[3], b1b[3])));
    uint4 pk = {lo.x, lo.y, hi.x, hi.y};
    *reinterpret_cast<uint4*>(&ub[e * 264 + dg * 8]) = pk;
  }
}

// ---------------- table build: tabF[n][d] = F(n*SDELTA)[d], fp32 out ----------------

__global__ __launch_bounds__(256, 3) void tab_kernel(
    const float* __restrict__ res_w1, const float* __restrict__ res_b1,
    const float* __restrict__ atom_w1, const float* __restrict__ atom_b1,
    const unsigned short* __restrict__ wpack, float* __restrict__ tabF) {
  __shared__ __align__(16) unsigned short ubuf[64 * 264];
  __shared__ float Sv[64];
  const int t = threadIdx.x, lane = t & 63, wv = t >> 6;
  const int l15 = lane & 15, l4 = lane >> 4;
  const int n0 = blockIdx.x * 64;
  if (t < 64) Sv[t] = (n0 + t) * SDELTA;
  __syncthreads();
  f32x4 acc[4][4];
  zero_acc4(acc);
  fill_u(ubuf, Sv, res_w1, res_b1, t);
  __syncthreads();
  gemm4(acc, wpack + 0 * 65536, ubuf, lane, wv);
  __syncthreads();
  fill_u(ubuf, Sv, atom_w1, atom_b1, t);
  __syncthreads();
  gemm4(acc, wpack + 1 * 65536, ubuf, lane, wv);
#pragma unroll
  for (int mt = 0; mt < 4; ++mt) {
    const int d = wv * 64 + mt * 16 + l4 * 4;
#pragma unroll
    for (int nt = 0; nt < 4; ++nt) {
      const int n = n0 + nt * 16 + l15;
      *reinterpret_cast<f32x4*>(&tabF[n * 256 + d]) = acc[mt][nt];
    }
  }
}

// ---------------- pairwise kernel (64-row tiles): fp32-table-interp h + 2 GEMMs -------
// R11 knob: __launch_bounds__(256,3) — raise the VGPR ceiling (64 -> ~170) so the
// unrolled h-fill can keep more tabF gathers in flight (memory-level parallelism).
// Theory: at 64 VGPR only ~2 of 8 unrolled gather iterations fit in regs -> exposed
// L2/L3 gather latency is pair's residual stall. Costs 1 block/CU of TLP (4 -> 3).
// LEDGER: rcp ok(-7us) | persistent-grid BAD | LDS-shrink BAD(spill) | TLP-double BAD.

__global__ __launch_bounds__(256, 3) void pair_kernel(
    const float* __restrict__ Xg, const float* __restrict__ tabF,
    const float* __restrict__ int_b2, const float* __restrict__ wg_b,
    const unsigned short* __restrict__ wpack, const float* __restrict__ cvec,
    const float* __restrict__ P1, const float* __restrict__ P2,
    const float* __restrict__ Hpl, const float* __restrict__ Her,
    float* __restrict__ ftri, unsigned short* __restrict__ Zsw) {
  __shared__ __align__(16) unsigned short ubuf[64 * 264];
  __shared__ float Sv[64];
  __shared__ float pc[DD];
  const int t = threadIdx.x, lane = t & 63, wv = t >> 6;
  const int l15 = lane & 15, l4 = lane >> 4;
  const int wg = (blockIdx.x & 7) * 288 + (blockIdx.x >> 3);  // bijective XCD swizzle
  const int p = wg / 6, cc = wg % 6, e0 = cc * 64;
  const int d0 = wv * 64;

  if (t < 64) {
    const int e = e0 + t;
    float dx = Xg[p * 42 + 3] - Xg[(NPAR + e) * 42 + 3];
    float dy = Xg[p * 42 + 4] - Xg[(NPAR + e) * 42 + 4];
    float dz = Xg[p * 42 + 5] - Xg[(NPAR + e) * 42 + 5];
    Sv[t] = dx * dx + dy * dy + dz * dz;
  }
  pc[t] = P1[p * DD + t] + cvec[t];
  __syncthreads();

  // h-fill: h[e][d] = silu(lerp(tabF, S[e])[d] + pc[d] + P2[e][d]) -> ubuf
  {
    const int dg = t & 31, rb = t >> 5;
    const f32x4 pca = *reinterpret_cast<const f32x4*>(&pc[dg * 8]);
    const f32x4 pcb = *reinterpret_cast<const f32x4*>(&pc[dg * 8 + 4]);
#pragma unroll
    for (int i = 0; i < 8; ++i) {
      const int e = rb + i * 8;
      float sv = Sv[e] * SINVD;
      int idx = (int)sv;
      idx = idx > (NTAB - 2) ? (NTAB - 2) : idx;
      const float fr = sv - (float)idx;
      const f32x4 t0a = *reinterpret_cast<const f32x4*>(&tabF[idx * 256 + dg * 8]);
      const f32x4 t0b = *reinterpret_cast<const f32x4*>(&tabF[idx * 256 + dg * 8 + 4]);
      const f32x4 t1a = *reinterpret_cast<const f32x4*>(&tabF[(idx + 1) * 256 + dg * 8]);
      const f32x4 t1b = *reinterpret_cast<const f32x4*>(&tabF[(idx + 1) * 256 + dg * 8 + 4]);
      const f32x4 p2a = *reinterpret_cast<const f32x4*>(&P2[(e0 + e) * DD + dg * 8]);
      const f32x4 p2b = *reinterpret_cast<const f32x4*>(&P2[(e0 + e) * DD + dg * 8 + 4]);
      float z0 = fmaf(fr, t1a[0] - t0a[0], t0a[0]) + pca[0] + p2a[0];
      float z1 = fmaf(fr, t1a[1] - t0a[1], t0a[1]) + pca[1] + p2a[1];
      float z2 = fmaf(fr, t1a[2] - t0a[2], t0a[2]) + pca[2] + p2a[2];
      float z3 = fmaf(fr, t1a[3] - t0a[3], t0a[3]) + pca[3] + p2a[3];
      float z4 = fmaf(fr, t1b[0] - t0b[0], t0b[0]) + pcb[0] + p2b[0];
      float z5 = fmaf(fr, t1b[1] - t0b[1], t0b[1]) + pcb[1] + p2b[1];
      float z6 = fmaf(fr, t1b[2] - t0b[2], t0b[2]) + pcb[2] + p2b[2];
      float z7 = fmaf(fr, t1b[3] - t0b[3], t0b[3]) + pcb[3] + p2b[3];
      uint2 lo = pack4(silu(z0), silu(z1), silu(z2), silu(z3));
      uint2 hi = pack4(silu(z4), silu(z5), silu(z6), silu(z7));
      uint4 pk = {lo.x, lo.y, hi.x, hi.y};
      *reinterpret_cast<uint4*>(&ubuf[e * 264 + dg * 8]) = pk;
    }
  }
  __syncthreads();

  // Z = h @ int_w2 + int_b2 -> ubuf
  f32x4 acc[4][4];
  zero_acc4(acc);
  gemm4(acc, wpack + 2 * 65536, ubuf, lane, wv);
  __syncthreads();
#pragma unroll
  for (int mt = 0; mt < 4; ++mt) {
    const int d = d0 + mt * 16 + l4 * 4;
    const f32x4 bb = *reinterpret_cast<const f32x4*>(&int_b2[d]);
#pragma unroll
    for (int nt = 0; nt < 4; ++nt) {
      const int e = nt * 16 + l15;
      *reinterpret_cast<uint2*>(&ubuf[e * 264 + d]) =
          pack4(acc[mt][nt][0] + bb[0], acc[mt][nt][1] + bb[1],
                acc[mt][nt][2] + bb[2], acc[mt][nt][3] + bb[3]);
    }
  }
  __syncthreads();

  // swizzled MFMA-fragment-order store: grp = cc*4 + wv, e = grp*16 + l15
  {
    unsigned short* Zd = Zsw + (size_t)p * 98304 + (size_t)(cc * 4 + wv) * 4096 + lane * 8;
#pragma unroll
    for (int ks = 0; ks < 8; ++ks) {
      *reinterpret_cast<uint4*>(Zd + ks * 512) =
          *reinterpret_cast<const uint4*>(&ubuf[(wv * 16 + l15) * 264 + ks * 32 + l4 * 8]);
    }
  }

  // gate: f_tri[d] += Hpl[p][d] * sum_e sigm(Z@wg + b) * Her[e][d]
  zero_acc4(acc);
  gemm4(acc, wpack + 3 * 65536, ubuf, lane, wv);
#pragma unroll
  for (int mt = 0; mt < 4; ++mt) {
    const int d = d0 + mt * 16 + l4 * 4;
    const f32x4 bb = *reinterpret_cast<const f32x4*>(&wg_b[d]);
    const f32x4 hl = *reinterpret_cast<const f32x4*>(&Hpl[p * DD + d]);
    f32x4 fs = (f32x4){0.f, 0.f, 0.f, 0.f};
#pragma unroll
    for (int nt = 0; nt < 4; ++nt) {
      const int e = e0 + nt * 16 + l15;
      const f32x4 hr = *reinterpret_cast<const f32x4*>(&Her[e * DD + d]);
#pragma unroll
      for (int r = 0; r < 4; ++r)
        fs[r] += sigm(acc[mt][nt][r] + bb[r]) * hr[r];
    }
#pragma unroll
    for (int r = 0; r < 4; ++r) {
      float v = fs[r] * hl[r];
      v += __shfl_xor(v, 1);
      v += __shfl_xor(v, 2);
      v += __shfl_xor(v, 4);
      v += __shfl_xor(v, 8);
      if (l15 == 0) atomicAdd(&ftri[p * DD + d + r], v);
    }
  }
}

// ---------------- fused attention kernel: block = (p, 64-row chunk), 8 waves --------
// 2304 blocks x 512 thr. Wave (q=wv&3, h=wv>>2): T' for d-quarter q of row-half h;
// S for rows h*32.. x col-streams j*4+q. Traffic-halving vs 32-row version was
// neutral (R10: -0.7us) -> attn latency-bound; kept for the principled traffic cut.

__global__ __launch_bounds__(512, 4) void attn_kernel(
    const unsigned short* __restrict__ Zsw, const float* __restrict__ gv,
    const unsigned short* __restrict__ wpack, float* __restrict__ cbufg) {
  __shared__ __align__(16) unsigned short Tc[64 * 264];
  __shared__ float red[256];
  __shared__ float red2[256];
  const int t = threadIdx.x, lane = t & 63, wv = t >> 6;   // wv 0..7
  const int q = wv & 3, h = wv >> 2;
  const int l15 = lane & 15, l4 = lane >> 4;
  const int xcd = blockIdx.x & 7, inner = blockIdx.x >> 3;  // 2304 = 8*288
  const int p = (inner / 6) * 8 + xcd, c = inner % 6;
  const unsigned short* Zsp = Zsw + (size_t)p * 98304;
  const unsigned short* wqk = wpack + 4 * 65536;

  // T' = (Zc @ Wqk + gv) / 16: rows h*32+{0..31} (groups c*4+h*2+nt), d-quarter q
  {
    f32x4 ta[4][2];
#pragma unroll
    for (int mt = 0; mt < 4; ++mt)
#pragma unroll
      for (int nt = 0; nt < 2; ++nt) ta[mt][nt] = (f32x4){0.f, 0.f, 0.f, 0.f};
    const unsigned short* Tb = Zsp + (size_t)(c * 4 + h * 2) * 4096 + lane * 8;
    bf16x8 bcur[2], bnxt[2];
#pragma unroll
    for (int nt = 0; nt < 2; ++nt)
      bcur[nt] = *reinterpret_cast<const bf16x8*>(Tb + nt * 4096);
#pragma unroll
    for (int ks = 0; ks < 8; ++ks) {
      if (ks < 7) {
#pragma unroll
        for (int nt = 0; nt < 2; ++nt)
          bnxt[nt] = *reinterpret_cast<const bf16x8*>(Tb + nt * 4096 + (ks + 1) * 512);
      }
      bf16x8 a[4];
#pragma unroll
      for (int mt = 0; mt < 4; ++mt)
        a[mt] = *reinterpret_cast<const bf16x8*>(wqk + ((ks * 16 + q * 4 + mt) * 64 + lane) * 8);
      __builtin_amdgcn_s_setprio(1);
#pragma unroll
      for (int nt = 0; nt < 2; ++nt)
#pragma unroll
        for (int mt = 0; mt < 4; ++mt)
          ta[mt][nt] = __builtin_amdgcn_mfma_f32_16x16x32_bf16(a[mt], bcur[nt], ta[mt][nt], 0, 0, 0);
      __builtin_amdgcn_s_setprio(0);
      if (ks < 7) {
#pragma unroll
        for (int nt = 0; nt < 2; ++nt) bcur[nt] = bnxt[nt];
      }
    }
#pragma unroll
    for (int mt = 0; mt < 4; ++mt) {
      const int d = q * 64 + mt * 16 + l4 * 4;
      const f32x4 gq = *reinterpret_cast<const f32x4*>(&gv[d]);
#pragma unroll
      for (int nt = 0; nt < 2; ++nt) {
        const int e = h * 32 + nt * 16 + l15;
        *reinterpret_cast<uint2*>(&Tc[e * 264 + d]) =
            pack4((ta[mt][nt][0] + gq[0]) * 0.0625f, (ta[mt][nt][1] + gq[1]) * 0.0625f,
                  (ta[mt][nt][2] + gq[2]) * 0.0625f, (ta[mt][nt][3] + gq[3]) * 0.0625f);
      }
    }
  }
  __syncthreads();

  // S = Tc @ Z^T; rows h*32.., col-streams j -> group j*4+q; 3+3 rolling prefetch
  f32x4 sc[2][6];
#pragma unroll
  for (int mt = 0; mt < 2; ++mt)
#pragma unroll
    for (int s = 0; s < 6; ++s) sc[mt][s] = (f32x4){0.f, 0.f, 0.f, 0.f};

  {
    const unsigned short* Sb = Zsp + (size_t)q * 4096 + lane * 8;
    bf16x8 b0[3], b1[3];
#pragma unroll
    for (int j = 0; j < 3; ++j)
      b0[j] = *reinterpret_cast<const bf16x8*>(Sb + j * 16384);
#pragma unroll
    for (int ks = 0; ks < 8; ++ks) {
#pragma unroll
      for (int j = 0; j < 3; ++j)
        b1[j] = *reinterpret_cast<const bf16x8*>(Sb + (3 + j) * 16384 + ks * 512);
      bf16x8 a[2];
#pragma unroll
      for (int mt = 0; mt < 2; ++mt)
        a[mt] = *reinterpret_cast<const bf16x8*>(&Tc[(h * 32 + mt * 16 + l15) * 264 + ks * 32 + l4 * 8]);
      __builtin_amdgcn_s_setprio(1);
#pragma unroll
      for (int j = 0; j < 3; ++j)
#pragma unroll
        for (int mt = 0; mt < 2; ++mt)
          sc[mt][j] = __builtin_amdgcn_mfma_f32_16x16x32_bf16(a[mt], b0[j], sc[mt][j], 0, 0, 0);
      __builtin_amdgcn_s_setprio(0);
      if (ks < 7) {
#pragma unroll
        for (int j = 0; j < 3; ++j)
          b0[j] = *reinterpret_cast<const bf16x8*>(Sb + j * 16384 + (ks + 1) * 512);
      }
      __builtin_amdgcn_s_setprio(1);
#pragma unroll
      for (int j = 0; j < 3; ++j)
#pragma unroll
        for (int mt = 0; mt < 2; ++mt)
          sc[mt][3 + j] = __builtin_amdgcn_mfma_f32_16x16x32_bf16(a[mt], b1[j], sc[mt][3 + j], 0, 0, 0);
      __builtin_amdgcn_s_setprio(0);
    }
  }

  // softmax over f (384 cols): rows row32 = mt*16+l4*4+r of row-half h;
  // cross-wave (4 q's) reduce via red[h*128 + q*32 + row32]
  float rmax[2][4];
#pragma unroll
  for (int mt = 0; mt < 2; ++mt) {
#pragma unroll
    for (int r = 0; r < 4; ++r) {
      float m = -1e30f;
#pragma unroll
      for (int s = 0; s < 6; ++s) m = fmaxf(m, sc[mt][s][r]);
      m = fmaxf(m, __shfl_xor(m, 1));
      m = fmaxf(m, __shfl_xor(m, 2));
      m = fmaxf(m, __shfl_xor(m, 4));
      m = fmaxf(m, __shfl_xor(m, 8));
      rmax[mt][r] = m;
    }
  }
  if (l15 == 0) {
#pragma unroll
    for (int mt = 0; mt < 2; ++mt)
#pragma unroll
      for (int r = 0; r < 4; ++r)
        red[h * 128 + q * 32 + mt * 16 + l4 * 4 + r] = rmax[mt][r];
  }
  __syncthreads();
#pragma unroll
  for (int mt = 0; mt < 2; ++mt) {
#pragma unroll
    for (int r = 0; r < 4; ++r) {
      const int base = h * 128 + mt * 16 + l4 * 4 + r;
      rmax[mt][r] = fmaxf(fmaxf(red[base], red[base + 32]),
                          fmaxf(red[base + 64], red[base + 96]));
    }
  }

  float rsum[2][4];
#pragma unroll
  for (int mt = 0; mt < 2; ++mt) {
#pragma unroll
    for (int r = 0; r < 4; ++r) {
      float sSum = 0.f;
#pragma unroll
      for (int s = 0; s < 6; ++s) {
        float e = __expf(sc[mt][s][r] - rmax[mt][r]);
        sc[mt][s][r] = e;
        sSum += e;
      }
      sSum += __shfl_xor(sSum, 1);
      sSum += __shfl_xor(sSum, 2);
      sSum += __shfl_xor(sSum, 4);
      sSum += __shfl_xor(sSum, 8);
      rsum[mt][r] = sSum;
    }
  }
  if (l15 == 0) {
#pragma unroll
    for (int mt = 0; mt < 2; ++mt)
#pragma unroll
      for (int r = 0; r < 4; ++r)
        red2[h * 128 + q * 32 + mt * 16 + l4 * 4 + r] = rsum[mt][r];
  }
  __syncthreads();
  float rinv[2][4];
#pragma unroll
  for (int mt = 0; mt < 2; ++mt) {
#pragma unroll
    for (int r = 0; r < 4; ++r) {
      const int base = h * 128 + mt * 16 + l4 * 4 + r;
      rinv[mt][r] = fastrcp(red2[base] + red2[base + 32] + red2[base + 64] + red2[base + 96]);
    }
  }

  // column sums of A over this wave's 32 rows -> cbufg (group s*4+q)
#pragma unroll
  for (int s = 0; s < 6; ++s) {
    float v = 0.f;
#pragma unroll
    for (int mt = 0; mt < 2; ++mt)
#pragma unroll
      for (int r = 0; r < 4; ++r)
        v += sc[mt][s][r] * rinv[mt][r];
    v += __shfl_xor(v, 16);
    v += __shfl_xor(v, 32);
    if (lane < 16)
      atomicAdd(&cbufg[p * NEPI + (s * 4 + q) * 16 + lane], v);
  }
}

// ---------------- fused output kernel: u[p] over all 24 groups + final epilogue ------

__global__ __launch_bounds__(256) void outf_kernel(
    const unsigned short* __restrict__ Zsw, const float* __restrict__ cbufg,
    const float* __restrict__ ftri, const float* __restrict__ wvw,
    const float* __restrict__ wvb, float* __restrict__ out) {
  __shared__ float cb[NEPI];
  __shared__ float part[16][257];
  __shared__ float u[DD];
  const int p = blockIdx.x;
  const int t = threadIdx.x;
  const int lane = t & 63, wv = t >> 6;
  const int l15 = lane & 15, l4 = lane >> 4;
  cb[t] = cbufg[p * NEPI + t];
  if (t < NEPI - 256) cb[256 + t] = cbufg[p * NEPI + 256 + t];
  __syncthreads();
  const unsigned short* Zsp = Zsw + (size_t)p * 98304;
  float a16[16];
#pragma unroll
  for (int j = 0; j < 16; ++j) a16[j] = 0.f;
  for (int grp = 0; grp < 24; ++grp) {
    const float w = cb[grp * 16 + l15];
    const uint4 z0 = *reinterpret_cast<const uint4*>(Zsp + grp * 4096 + wv * 512 + lane * 8);
    const uint4 z1 = *reinterpret_cast<const uint4*>(Zsp + grp * 4096 + (wv + 4) * 512 + lane * 8);
    a16[0] = fmaf(w, bf2f(z0.x & 0xffffu), a16[0]);
    a16[1] = fmaf(w, bf2f(z0.x >> 16), a16[1]);
    a16[2] = fmaf(w, bf2f(z0.y & 0xffffu), a16[2]);
    a16[3] = fmaf(w, bf2f(z0.y >> 16), a16[3]);
    a16[4] = fmaf(w, bf2f(z0.z & 0xffffu), a16[4]);
    a16[5] = fmaf(w, bf2f(z0.z >> 16), a16[5]);
    a16[6] = fmaf(w, bf2f(z0.w & 0xffffu), a16[6]);
    a16[7] = fmaf(w, bf2f(z0.w >> 16), a16[7]);
    a16[8]  = fmaf(w, bf2f(z1.x & 0xffffu), a16[8]);
    a16[9]  = fmaf(w, bf2f(z1.x >> 16), a16[9]);
    a16[10] = fmaf(w, bf2f(z1.y & 0xffffu), a16[10]);
    a16[11] = fmaf(w, bf2f(z1.y >> 16), a16[11]);
    a16[12] = fmaf(w, bf2f(z1.z & 0xffffu), a16[12]);
    a16[13] = fmaf(w, bf2f(z1.z >> 16), a16[13]);
    a16[14] = fmaf(w, bf2f(z1.w & 0xffffu), a16[14]);
    a16[15] = fmaf(w, bf2f(z1.w >> 16), a16[15]);
  }
#pragma unroll
  for (int j = 0; j < 8; ++j) part[l15][wv * 32 + l4 * 8 + j] = a16[j];
#pragma unroll
  for (int j = 0; j < 8; ++j) part[l15][128 + wv * 32 + l4 * 8 + j] = a16[8 + j];
  __syncthreads();
  float uu = 0.f;
#pragma unroll
  for (int g = 0; g < 16; ++g) uu += part[g][t];
  u[t] = uu;
  __syncthreads();
  float acc = ftri[p * DD + t] + 384.0f * wvb[t];
#pragma unroll 8
  for (int d = 0; d < DD; ++d)
    acc = fmaf(u[d], wvw[d * DD + t], acc);
  out[p * DD + t] = acc * (1.0f / 384.0f);
}

// ---------------- launch ----------------

extern "C" void kernel_launch(void* const* d_in, const int* in_sizes, int n_in,
                              void* d_out, int out_size, void* d_ws, size_t ws_size,
                              hipStream_t stream) {
  (void)in_sizes; (void)n_in; (void)out_size; (void)ws_size;
  const float* H = (const float*)d_in[0];
  const float* X = (const float*)d_in[1];
  const float* res_w1 = (const float*)d_in[4];
  const float* res_b1 = (const float*)d_in[5];
  const float* res_w2 = (const float*)d_in[6];
  const float* res_b2 = (const float*)d_in[7];
  const float* atom_w1 = (const float*)d_in[8];
  const float* atom_b1 = (const float*)d_in[9];
  const float* atom_w2 = (const float*)d_in[10];
  const float* atom_b2 = (const float*)d_in[11];
  const float* simw = (const float*)d_in[12];
  const float* int_w1 = (const float*)d_in[13];
  const float* int_b1 = (const float*)d_in[14];
  const float* int_w2 = (const float*)d_in[15];
  const float* int_b2 = (const float*)d_in[16];
  const float* wl = (const float*)d_in[17];
  const float* wr = (const float*)d_in[18];
  const float* wg_w = (const float*)d_in[19];
  const float* wg_b = (const float*)d_in[20];
  const float* wq_w = (const float*)d_in[21];
  const float* wq_b = (const float*)d_in[22];
  const float* wk_w = (const float*)d_in[23];
  const float* wv_w = (const float*)d_in[25];
  const float* wv_b = (const float*)d_in[26];

  char* ws = (char*)d_ws;
  unsigned short* wpack = (unsigned short*)(ws + 0);      //  655360 B (5 slots)
  float* cvec  = (float*)(ws + 655360);                   //    1024 B
  float* gv    = (float*)(ws + 656384);                   //    1024 B
  float* P1    = (float*)(ws + 657408);                   //  393216 B
  float* P2    = (float*)(ws + 1050624);                  //  393216 B
  float* Hpl   = (float*)(ws + 1443840);                  //  393216 B
  float* Her   = (float*)(ws + 1837056);                  //  393216 B
  float* ftri  = (float*)(ws + 2230272);                  //  393216 B
  float* cbufg = (float*)(ws + 2623488);                  //  589824 B
  unsigned short* Zsw = (unsigned short*)(ws + 3606528);  // 75497472 B
  float* tabF  = (float*)(ws + 79104000);                 //  4194304 B (NTAB x 256 fp32)

  // independent of all kernels: overlap the H-tail copy with the kernel chain
  hipMemcpyAsync((float*)d_out + NPAR * DD, H + NPAR * DD,
                 (1024 - NPAR) * DD * sizeof(float), hipMemcpyDeviceToDevice, stream);
  hipMemsetAsync(ftri, 0, 393216 + 589824, stream);   // ftri + cbufg
  prep_kernel<<<1473, 256, 0, stream>>>(H, wl, wr, int_w1, res_w2, atom_w2,
                                        res_b2, atom_b2, int_b1, simw, wq_b, wk_w,
                                        wq_w, int_w2, wg_w,
                                        Hpl, Her, P1, P2, cvec, gv, wpack);
  tab_kernel<<<NTAB / 64, 256, 0, stream>>>(res_w1, res_b1, atom_w1, atom_b1, wpack, tabF);
  pair_kernel<<<2304, 256, 0, stream>>>(X, tabF, int_b2, wg_b, wpack, cvec,
                                        P1, P2, Hpl, Her, ftri, Zsw);
  attn_kernel<<<2304, 512, 0, stream>>>(Zsw, gv, wpack, cbufg);
  outf_kernel<<<384, 256, 0, stream>>>(Zsw, cbufg, ftri, wv_w, wv_b, (float*)d_out);
}